// Round 16
// baseline (254.831 us; speedup 1.0000x reference)
//
#include <hip/hip_runtime.h>
#include <math.h>

#define L 2048
#define DM 512
#define B_ 8
#define H_ 8
#define DH 64
#define SK 24
#define NTOP 24
#define CHUNK 128
#define NCH (L / CHUNK)   // 16
#define VC 32             // vavg chunks
#define VR 64             // rows per vavg chunk
#define ABUF 4096         // u16 per LDS gemm buffer (128 rows x 32 k)

typedef __attribute__((ext_vector_type(8))) short short8;
typedef __attribute__((ext_vector_type(8))) __bf16 bf16x8;
typedef __attribute__((ext_vector_type(4))) float f32x4;

__device__ inline unsigned short f2bf(float x) {
    unsigned u = __float_as_uint(x);
    unsigned r = (u + 0x7FFFu + ((u >> 16) & 1u)) >> 16;
    return (unsigned short)r;
}
__device__ inline float bf2f(unsigned short h) {
    return __uint_as_float(((unsigned)h) << 16);
}

__device__ inline f32x4 MFMA_BF16(short8 a, short8 b, f32x4 c) {
    return __builtin_amdgcn_mfma_f32_16x16x32_bf16(
        __builtin_bit_cast(bf16x8, a), __builtin_bit_cast(bf16x8, b), c, 0, 0, 0);
}

// async global->LDS, 16B per lane; LDS dest = wave-uniform base + lane*16
__device__ __forceinline__ void gload16(const unsigned short* g, unsigned short* l) {
    __builtin_amdgcn_global_load_lds(
        (const __attribute__((address_space(1))) void*)g,
        (__attribute__((address_space(3))) void*)l, 16, 0, 0);
}

// convert 8 f32 (two float4) to bf16 hi (and optionally lo) short8
template<bool WANTL>
__device__ inline void cvt8(const float4& x, const float4& y, short8& h, short8& l) {
    float v0 = x.x, v1 = x.y, v2 = x.z, v3 = x.w;
    float v4 = y.x, v5 = y.y, v6 = y.z, v7 = y.w;
    unsigned short h0 = f2bf(v0), h1 = f2bf(v1), h2 = f2bf(v2), h3 = f2bf(v3);
    unsigned short h4 = f2bf(v4), h5 = f2bf(v5), h6 = f2bf(v6), h7 = f2bf(v7);
    h[0] = (short)h0; h[1] = (short)h1; h[2] = (short)h2; h[3] = (short)h3;
    h[4] = (short)h4; h[5] = (short)h5; h[6] = (short)h6; h[7] = (short)h7;
    if (WANTL) {
        l[0] = (short)f2bf(v0 - bf2f(h0)); l[1] = (short)f2bf(v1 - bf2f(h1));
        l[2] = (short)f2bf(v2 - bf2f(h2)); l[3] = (short)f2bf(v3 - bf2f(h3));
        l[4] = (short)f2bf(v4 - bf2f(h4)); l[5] = (short)f2bf(v5 - bf2f(h5));
        l[6] = (short)f2bf(v6 - bf2f(h6)); l[7] = (short)f2bf(v7 - bf2f(h7));
    }
}

// swizzled LDS address: conflict-free stores, 2-way (free) reads; no padding.
// (verified r12/r13: SQ_LDS_BANK_CONFLICT == 0)
__device__ inline int lds_addr(int row, int kblk) {
    return row * 32 + ((kblk ^ ((row >> 1) & 3)) << 3);
}

// ---------------- reduce helpers ----------------
__device__ inline float waveReduceSum(float v) {
    for (int o = 32; o > 0; o >>= 1) v += __shfl_down(v, o, 64);
    return v;
}
__device__ inline float waveReduceMax(float v) {
    for (int o = 32; o > 0; o >>= 1) v = fmaxf(v, __shfl_down(v, o, 64));
    return v;
}

// ---------------- LayerNorm (row-wise, 512 cols) f32 out ----------------
__global__ __launch_bounds__(256)
void ln_kernel(const float* __restrict__ x, const float* __restrict__ w,
               const float* __restrict__ bvec, float* __restrict__ out) {
    int row = blockIdx.x;
    const float* xr = x + (size_t)row * DM;
    float* orow = out + (size_t)row * DM;
    int tid = threadIdx.x;
    float2 v = *(const float2*)(xr + tid * 2);
    float s = v.x + v.y;
    float sq = v.x * v.x + v.y * v.y;
    __shared__ float red[8];
    float ws = waveReduceSum(s);
    float wq = waveReduceSum(sq);
    int wid = tid >> 6, lane = tid & 63;
    if (lane == 0) { red[wid] = ws; red[4 + wid] = wq; }
    __syncthreads();
    float tot = red[0] + red[1] + red[2] + red[3];
    float totq = red[4] + red[5] + red[6] + red[7];
    float mean = tot * (1.0f / DM);
    float var = totq * (1.0f / DM) - mean * mean;
    float inv = rsqrtf(var + 1e-8f);
    float w0 = w[tid * 2], w1 = w[tid * 2 + 1];
    float b0 = bvec[tid * 2], b1 = bvec[tid * 2 + 1];
    float2 o;
    o.x = w0 * (v.x - mean) * inv + b0;
    o.y = w1 * (v.y - mean) * inv + b1;
    *(float2*)(orow + tid * 2) = o;
}

// ---------------- LayerNorm with bf16 hi/lo split output ----------------
__global__ __launch_bounds__(256)
void ln_split_kernel(const float* __restrict__ x, const float* __restrict__ w,
                     const float* __restrict__ bvec,
                     unsigned short* __restrict__ oh, unsigned short* __restrict__ ol) {
    int row = blockIdx.x;
    const float* xr = x + (size_t)row * DM;
    int tid = threadIdx.x;
    float2 v = *(const float2*)(xr + tid * 2);
    float s = v.x + v.y;
    float sq = v.x * v.x + v.y * v.y;
    __shared__ float red[8];
    float ws = waveReduceSum(s);
    float wq = waveReduceSum(sq);
    int wid = tid >> 6, lane = tid & 63;
    if (lane == 0) { red[wid] = ws; red[4 + wid] = wq; }
    __syncthreads();
    float tot = red[0] + red[1] + red[2] + red[3];
    float totq = red[4] + red[5] + red[6] + red[7];
    float mean = tot * (1.0f / DM);
    float var = totq * (1.0f / DM) - mean * mean;
    float inv = rsqrtf(var + 1e-8f);
    float w0 = w[tid * 2], w1 = w[tid * 2 + 1];
    float b0 = bvec[tid * 2], b1 = bvec[tid * 2 + 1];
    float o0 = w0 * (v.x - mean) * inv + b0;
    float o1 = w1 * (v.y - mean) * inv + b1;
    ushort2 hh, ll;
    hh.x = f2bf(o0); ll.x = f2bf(o0 - bf2f(hh.x));
    hh.y = f2bf(o1); ll.y = f2bf(o1 - bf2f(hh.y));
    *(ushort2*)(oh + (size_t)row * DM + tid * 2) = hh;
    *(ushort2*)(ol + (size_t)row * DM + tid * 2) = ll;
}

// ---------------- W transpose + hi/lo split: Wt[n][k] = W[k][n] ----------------
__global__ __launch_bounds__(256)
void wsplit_kernel(const float* __restrict__ W, unsigned short* __restrict__ th,
                   unsigned short* __restrict__ tl) {
    __shared__ float ts[32][33];
    int k0 = blockIdx.y * 32, n0 = blockIdx.x * 32;
    int t = threadIdx.x;
    int r = t >> 3, c = (t & 7) * 4;
    float4 v = *(const float4*)(W + (size_t)(k0 + r) * 512 + n0 + c);
    ts[r][c] = v.x; ts[r][c + 1] = v.y; ts[r][c + 2] = v.z; ts[r][c + 3] = v.w;
    __syncthreads();
    float a0 = ts[c + 0][r], a1 = ts[c + 1][r], a2 = ts[c + 2][r], a3 = ts[c + 3][r];
    ushort4 h, l;
    h.x = f2bf(a0); l.x = f2bf(a0 - bf2f(h.x));
    h.y = f2bf(a1); l.y = f2bf(a1 - bf2f(h.y));
    h.z = f2bf(a2); l.z = f2bf(a2 - bf2f(h.z));
    h.w = f2bf(a3); l.w = f2bf(a3 - bf2f(h.w));
    *(ushort4*)(th + (size_t)(n0 + r) * 512 + k0 + c) = h;
    *(ushort4*)(tl + (size_t)(n0 + r) * 512 + k0 + c) = l;
}

// ---------------- MFMA split GEMM body, 128x128 tile ----------------
// A: reg-staged single-buffer (swizzled ds_write). B: global_load_lds width=16,
// double-buffered, with PRE-SWIZZLED per-lane global source so the linear LDS
// image equals the swizzled layout (rule: linear dest + inv-swz source + swz read)
// -> reads identical to r13/r15, bit-identical output.
// TERMS: 3 = Ah*Bh + Ah*Bl + Al*Bh, 2 = Ah*Bh + Ah*Bl, 1 = Ah*Bh
// OMODE: 0 = f32 only, 1 = f32 + bf16 mirror, 2 = bf16 only
// ACVT : 0 = A pre-split bf16 (Ah/Al), 1 = A f32 (Af), hi/lo in-register
template<int TERMS, int OMODE, int ACVT>
__device__ __forceinline__
void gemm_body(unsigned short* smem,
               const unsigned short* __restrict__ Ah, const unsigned short* __restrict__ Al,
               const float* __restrict__ Af,
               const unsigned short* __restrict__ Bh, const unsigned short* __restrict__ Bl,
               const float* __restrict__ bias, float* __restrict__ C,
               unsigned short* __restrict__ Ch, int orig) {
    constexpr int A_ARR = (TERMS == 3) ? 2 : 1;
    constexpr int B_ARR = (TERMS >= 2) ? 2 : 1;
    unsigned short* sAh = smem;
    unsigned short* sAl = smem + ABUF;                // used only when TERMS==3
    unsigned short* sB  = smem + A_ARR * ABUF;        // [buf][arr][ABUF]

    int j = (orig & 7) * 64 + (orig >> 3);
    int n0 = (j & 3) * 128, m0 = (j >> 2) * 128;

    int tid = threadIdx.x;
    int lane = tid & 63, wv = tid >> 6;
    int wr = wv >> 1, wc = wv & 1;
    int lrow = lane & 15, g = lane >> 4;

    int row0 = tid >> 2, k0b = tid & 3;   // A slot0: rows [0,64)
    int row1 = row0 + 64;                 // A slot1: rows [64,128)
    int sa0 = lds_addr(row0, k0b), sa1 = lds_addr(row1, k0b);
    int c0 = k0b * 8;

    f32x4 acc[4][4];
#pragma unroll
    for (int mf = 0; mf < 4; mf++)
#pragma unroll
        for (int nf = 0; nf < 4; nf++) acc[mf][nf] = (f32x4){0.f, 0.f, 0.f, 0.f};

    short8 rAh0, rAh1, rAl0, rAl1;
    float4 fA00, fA01, fA10, fA11;

    auto LOAD_A = [&](int kt) {
        int k0 = kt * 32;
        if (ACVT) {
            fA00 = *(const float4*)(Af + (size_t)(m0 + row0) * 512 + k0 + c0);
            fA01 = *(const float4*)(Af + (size_t)(m0 + row0) * 512 + k0 + c0 + 4);
            fA10 = *(const float4*)(Af + (size_t)(m0 + row1) * 512 + k0 + c0);
            fA11 = *(const float4*)(Af + (size_t)(m0 + row1) * 512 + k0 + c0 + 4);
        } else {
            rAh0 = *(const short8*)(Ah + (size_t)(m0 + row0) * 512 + k0 + c0);
            rAh1 = *(const short8*)(Ah + (size_t)(m0 + row1) * 512 + k0 + c0);
            if (TERMS == 3) {
                rAl0 = *(const short8*)(Al + (size_t)(m0 + row0) * 512 + k0 + c0);
                rAl1 = *(const short8*)(Al + (size_t)(m0 + row1) * 512 + k0 + c0);
            }
        }
    };
    auto STORE_A = [&]() {
        if (ACVT) {
            cvt8<TERMS == 3>(fA00, fA01, rAh0, rAl0);
            cvt8<TERMS == 3>(fA10, fA11, rAh1, rAl1);
        }
        *(short8*)&sAh[sa0] = rAh0;
        *(short8*)&sAh[sa1] = rAh1;
        if (TERMS == 3) {
            *(short8*)&sAl[sa0] = rAl0;
            *(short8*)&sAl[sa1] = rAl1;
        }
    };
    // B async staging: per wave, slot0 = rows [wv*16, +16), slot1 = +64.
    // lane -> (row = base + (lane>>2), kpos = lane&3); source column pre-swizzled.
    auto GLOAD_B = [&](int kt, int buf) {
        int k0 = kt * 32;
        int r0 = wv * 16 + (lane >> 2);
        int kpos = lane & 3;
        int src0 = (kpos ^ ((r0 >> 1) & 3)) * 8;
        int r1 = r0 + 64;
        int src1 = (kpos ^ ((r1 >> 1) & 3)) * 8;
        unsigned short* bh = sB + (buf * B_ARR + 0) * ABUF;
        gload16(Bh + (size_t)(n0 + r0) * 512 + k0 + src0, bh + wv * 512);
        gload16(Bh + (size_t)(n0 + r1) * 512 + k0 + src1, bh + 2048 + wv * 512);
        if (TERMS >= 2) {
            unsigned short* bl = sB + (buf * B_ARR + 1) * ABUF;
            gload16(Bl + (size_t)(n0 + r0) * 512 + k0 + src0, bl + wv * 512);
            gload16(Bl + (size_t)(n0 + r1) * 512 + k0 + src1, bl + 2048 + wv * 512);
        }
    };

    int ra = wr * 64 + lrow;
    int rb = wc * 64 + lrow;
    int abase = ra * 32 + ((g ^ ((ra >> 1) & 3)) << 3);
    int bbase = rb * 32 + ((g ^ ((rb >> 1) & 3)) << 3);

    LOAD_A(0);
    GLOAD_B(0, 0);
    for (int kt = 0; kt < 16; kt++) {
        STORE_A();
        __syncthreads();                  // A stores visible; gload(kt) drained
        if (kt < 15) { GLOAD_B(kt + 1, (kt + 1) & 1); LOAD_A(kt + 1); }
        const unsigned short* bhB = sB + ((kt & 1) * B_ARR + 0) * ABUF;
        const unsigned short* blB = sB + ((kt & 1) * B_ARR + 1) * ABUF;
        short8 ah[4], al[4], bh[4], bl[4];
#pragma unroll
        for (int mf = 0; mf < 4; mf++) {
            ah[mf] = *(const short8*)&sAh[abase + mf * 512];
            if (TERMS == 3) al[mf] = *(const short8*)&sAl[abase + mf * 512];
        }
#pragma unroll
        for (int nf = 0; nf < 4; nf++) {
            bh[nf] = *(const short8*)&bhB[bbase + nf * 512];
            if (TERMS >= 2) bl[nf] = *(const short8*)&blB[bbase + nf * 512];
        }
#pragma unroll
        for (int mf = 0; mf < 4; mf++)
#pragma unroll
            for (int nf = 0; nf < 4; nf++) {
                acc[mf][nf] = MFMA_BF16(ah[mf], bh[nf], acc[mf][nf]);
                if (TERMS >= 2) acc[mf][nf] = MFMA_BF16(ah[mf], bl[nf], acc[mf][nf]);
                if (TERMS == 3) acc[mf][nf] = MFMA_BF16(al[mf], bh[nf], acc[mf][nf]);
            }
        __syncthreads();                  // A reads done before next STORE_A
    }

    int crow0 = m0 + wr * 64 + (lane >> 4) * 4;
    int ccol0 = n0 + wc * 64 + lrow;
    float bb[4];
#pragma unroll
    for (int nf = 0; nf < 4; nf++) bb[nf] = bias[ccol0 + nf * 16];
#pragma unroll
    for (int mf = 0; mf < 4; mf++)
#pragma unroll
        for (int nf = 0; nf < 4; nf++)
#pragma unroll
            for (int r = 0; r < 4; r++) {
                float val = acc[mf][nf][r] + bb[nf];
                size_t idx = (size_t)(crow0 + mf * 16 + r) * 512 + ccol0 + nf * 16;
                if (OMODE != 2) C[idx] = val;
                if (OMODE != 0) Ch[idx] = f2bf(val);
            }
}

// fused Q/K/V GEMM (blockIdx.z selects sub-GEMM); 48KB LDS worst case
__global__ __launch_bounds__(256, 2)
void qkv_gemm(const unsigned short* __restrict__ lnq_h, const unsigned short* __restrict__ lnq_l,
              const float* __restrict__ keys, const float* __restrict__ values,
              const unsigned short* __restrict__ wq_h, const unsigned short* __restrict__ wq_l,
              const unsigned short* __restrict__ wk_h, const unsigned short* __restrict__ wk_l,
              const unsigned short* __restrict__ wv_h, const unsigned short* __restrict__ wv_l,
              const float* __restrict__ bq, const float* __restrict__ bk, const float* __restrict__ bv,
              float* __restrict__ qb, float* __restrict__ kb,
              unsigned short* __restrict__ kb_h, unsigned short* __restrict__ vb_h) {
    __shared__ __align__(16) unsigned short smem[6 * ABUF];  // 48KB: A 2 + B 2x2
    int orig = blockIdx.x + 4 * blockIdx.y;
    if (blockIdx.z == 0)
        gemm_body<3, 0, 0>(smem, lnq_h, lnq_l, nullptr, wq_h, wq_l, bq, qb, nullptr, orig);
    else if (blockIdx.z == 1)
        gemm_body<3, 1, 1>(smem, nullptr, nullptr, keys, wk_h, wk_l, bk, kb, kb_h, orig);
    else
        gemm_body<1, 2, 1>(smem, nullptr, nullptr, values, wv_h, wv_l, bv, nullptr, vb_h, orig);
}

// standalone (final F-GEMM, 1-term -> A 1 + B 2 = 24KB LDS)
template<int TERMS, int OMODE, int ACVT>
__global__ __launch_bounds__(256, 2)
void gemm_mfma(const unsigned short* __restrict__ Ah, const unsigned short* __restrict__ Al,
               const float* __restrict__ Af,
               const unsigned short* __restrict__ Bh, const unsigned short* __restrict__ Bl,
               const float* __restrict__ bias, float* __restrict__ C,
               unsigned short* __restrict__ Ch) {
    constexpr int NB = ((TERMS == 3) ? 2 : 1) + ((TERMS >= 2) ? 4 : 2);
    __shared__ __align__(16) unsigned short smem[NB * ABUF];
    int orig = blockIdx.x + 4 * blockIdx.y;
    gemm_body<TERMS, OMODE, ACVT>(smem, Ah, Al, Af, Bh, Bl, bias, C, Ch, orig);
}

// ---------------- sampled QK^T -> M (deferred reduction, independent gathers) ----
__global__ __launch_bounds__(256)
void sample_m_kernel(const float* __restrict__ q, const float* __restrict__ k,
                     const int* __restrict__ idx, float* __restrict__ M) {
    int bid = blockIdx.x;          // 4096
    int b = bid & 7;
    int ig = bid >> 3;             // 0..511
    int wv = threadIdx.x >> 6, lane = threadIdx.x & 63;
    int i = ig * 4 + wv;
    const float* qrow = q + ((size_t)b * L + i) * DM + lane * 8;
    float4 q0 = *(const float4*)qrow;
    float4 q1 = *(const float4*)(qrow + 4);
    int myidx = 0;
    if (lane < SK) myidx = idx[i * SK + lane];
    float sj[SK];
#pragma unroll
    for (int j = 0; j < SK; j++) {
        int row = __shfl(myidx, j, 64);
        const float* kp = k + ((size_t)b * L + row) * DM + lane * 8;
        float4 k0 = *(const float4*)kp;
        float4 k1 = *(const float4*)(kp + 4);
        sj[j] = q0.x * k0.x + q0.y * k0.y + q0.z * k0.z + q0.w * k0.w
              + q1.x * k1.x + q1.y * k1.y + q1.z * k1.z + q1.w * k1.w;
    }
    float mx = -1e30f, sm = 0.f;
#pragma unroll
    for (int j = 0; j < SK; j++) {
        float s = sj[j];
        s += __shfl_xor(s, 1, 64);
        s += __shfl_xor(s, 2, 64);
        s += __shfl_xor(s, 4, 64);
        mx = fmaxf(mx, s);
        sm += s;
    }
    if ((lane & 7) == 0) {
        int h = lane >> 3;
        M[((size_t)b * H_ + h) * L + i] = mx - sm * (1.0f / L);
    }
}

// ---------------- top-24 per (b,h): one wave, register-resident, no barriers ----------------
__global__ __launch_bounds__(64)
void topk_kernel(const float* __restrict__ M, int* __restrict__ mtop) {
    int bh = blockIdx.x;
    int lane = threadIdx.x;
    const float* Mr = M + (size_t)bh * L;
    float m[32];
#pragma unroll
    for (int r = 0; r < 32; r++) m[r] = Mr[r * 64 + lane];
    for (int it = 0; it < NTOP; it++) {
        float bv = -1e30f; int br = 0;
#pragma unroll
        for (int r = 0; r < 32; r++) {
            bool better = m[r] > bv;     // strict > keeps lowest r (lowest t) on ties
            br = better ? r : br;
            bv = better ? m[r] : bv;
        }
        int bt = (br << 6) | lane;
#pragma unroll
        for (int o = 1; o < 64; o <<= 1) {
            float ov = __shfl_xor(bv, o, 64);
            int ot = __shfl_xor(bt, o, 64);
            bool take = (ov > bv) || (ov == bv && ot < bt);
            bv = take ? ov : bv;
            bt = take ? ot : bt;
        }
        if (lane == 0) mtop[bh * NTOP + it] = bt;
        int rwin = bt >> 6;
        bool mine = (bt & 63) == lane;
#pragma unroll
        for (int r = 0; r < 32; r++)
            if (mine && (r == rwin)) m[r] = -1e30f;
    }
}

// ---------------- Q gather + pre-scale + lim prep (parallel) ----------------
__global__ __launch_bounds__(256)
void qprep_kernel(const float* __restrict__ qb, const int* __restrict__ mtop,
                  const float* __restrict__ pad, unsigned short* __restrict__ qsel,
                  int* __restrict__ lim_arr) {
    int bh = blockIdx.x; int b = bh >> 3, h = bh & 7;
    int tid = threadIdx.x;
#pragma unroll
    for (int l = 0; l < 2; l++) {
        int f = tid + l * 256;        // 0..511
        int u = f >> 4, seg = (f & 15) * 4;
        ushort4 o;
        if (u < NTOP) {
            int iq = mtop[bh * NTOP + u];
            bool ok = pad[(size_t)b * L + iq] != 0.f;
            float sc = ok ? 0.044194173824159216f : 0.f;
            float4 qv = *(const float4*)(qb + ((size_t)b * L + iq) * DM + h * DH + seg);
            o.x = f2bf(qv.x * sc); o.y = f2bf(qv.y * sc);
            o.z = f2bf(qv.z * sc); o.w = f2bf(qv.w * sc);
            if (seg == 0) lim_arr[bh * 32 + u] = ok ? iq : (L - 1);
        } else {
            o.x = o.y = o.z = o.w = 0;
            if (seg == 0) lim_arr[bh * 32 + u] = -1;
        }
        *(ushort4*)(qsel + ((size_t)bh * 32 + u) * 64 + seg) = o;
    }
}

// ---------------- padding cumsum ----------------
__global__ __launch_bounds__(256)
void padscan_kernel(const float* __restrict__ pad, float* __restrict__ denom) {
    int b = blockIdx.x;
    __shared__ float tot[256];
    int tid = threadIdx.x;
    const float* p = pad + (size_t)b * L;
    float loc[8];
    float s = 0.f;
#pragma unroll
    for (int u = 0; u < 8; u++) { s += p[tid * 8 + u]; loc[u] = s; }
    tot[tid] = s;
    __syncthreads();
    for (int off = 1; off < 256; off <<= 1) {
        float add = (tid >= off) ? tot[tid - off] : 0.f;
        __syncthreads();
        tot[tid] += add;
        __syncthreads();
    }
    float excl = tot[tid] - s;
#pragma unroll
    for (int u = 0; u < 8; u++) denom[(size_t)b * L + tid * 8 + u] = excl + loc[u];
}

// ---------------- cumulative average of V (bf16 in, 2 passes) ----------------
__global__ __launch_bounds__(256)
void vsum_kernel(const unsigned short* __restrict__ vh, float* __restrict__ csum) {
    int c = blockIdx.x, b = blockIdx.y;
    int d2 = threadIdx.x;
    size_t base = ((size_t)b * L + c * VR) * DM + d2 * 2;
    float a0 = 0.f, a1 = 0.f;
    for (int t = 0; t < VR; t++) {
        unsigned v = *(const unsigned*)(vh + base + (size_t)t * DM);
        a0 += bf2f((unsigned short)(v & 0xffff));
        a1 += bf2f((unsigned short)(v >> 16));
    }
    float2 st = {a0, a1};
    *(float2*)(csum + ((size_t)b * VC + c) * DM + d2 * 2) = st;
}

__global__ __launch_bounds__(256)
void vavg_kernel(const unsigned short* __restrict__ vh, const float* __restrict__ csum,
                 const float* __restrict__ denom, unsigned short* __restrict__ out_h) {
    int c = blockIdx.x, b = blockIdx.y;
    int d2 = threadIdx.x;
    float a0 = 0.f, a1 = 0.f;
    for (int cc = 0; cc < c; cc++) {
        float2 t = *(const float2*)(csum + ((size_t)b * VC + cc) * DM + d2 * 2);
        a0 += t.x; a1 += t.y;
    }
    size_t base = ((size_t)b * L + c * VR) * DM + d2 * 2;
    for (int t = 0; t < VR; t++) {
        unsigned v = *(const unsigned*)(vh + base + (size_t)t * DM);
        a0 += bf2f((unsigned short)(v & 0xffff));
        a1 += bf2f((unsigned short)(v >> 16));
        float dn = denom[(size_t)b * L + c * VR + t] + 1e-12f;
        unsigned o = (unsigned)f2bf(a0 / dn) | ((unsigned)f2bf(a1 / dn) << 16);
        *(unsigned*)(out_h + base + (size_t)t * DM) = o;
    }
}

// ---------------- MFMA split-chunk sparse attention ----------------
__global__ __launch_bounds__(256)
void attn_chunk_mfma(const unsigned short* __restrict__ kbh,
                     const unsigned short* __restrict__ vbh,
                     const unsigned short* __restrict__ qsel,
                     const int* __restrict__ lim_arr,
                     float* __restrict__ part_m, float* __restrict__ part_s,
                     float* __restrict__ part_acc) {
    int c = blockIdx.x, bh = blockIdx.y;
    int b = bh >> 3, h = bh & 7;
    int j0 = c * CHUNK;
    __shared__ __align__(16) unsigned short KV[128 * 64];
    __shared__ __align__(16) unsigned short Ps[32 * 128];
    __shared__ __align__(16) unsigned short Qs[32 * 64];
    __shared__ float redm[4][32];
    __shared__ float reds[4][32];
    __shared__ int lims[32];

    int tid = threadIdx.x;
    int wv = tid >> 6, lane = tid & 63;
    int l15 = lane & 15, g = lane >> 4;

    const unsigned short* kpanel = kbh + ((size_t)b * L + j0) * DM + h * DH;
    short8 kreg[4];
#pragma unroll
    for (int l = 0; l < 4; l++) {
        int f = tid + l * 256;
        int jr = f >> 3, blk = f & 7;
        kreg[l] = *(const short8*)(kpanel + (size_t)jr * DM + blk * 8);
    }
    {
        int u = tid >> 3, blk = tid & 7;
        short8 qreg = *(const short8*)(qsel + ((size_t)bh * 32 + u) * 64 + blk * 8);
        *(short8*)&Qs[u * 64 + (((blk ^ (u & 7))) << 3)] = qreg;
    }
#pragma unroll
    for (int l = 0; l < 4; l++) {
        int f = tid + l * 256;
        int jr = f >> 3, blk = f & 7;
        *(short8*)&KV[jr * 64 + ((blk ^ (jr & 7)) << 3)] = kreg[l];
    }
    if (tid < 32) lims[tid] = lim_arr[bh * 32 + tid];
    __syncthreads();

    f32x4 sf[2][2];
#pragma unroll
    for (int mf = 0; mf < 2; mf++)
#pragma unroll
        for (int nf = 0; nf < 2; nf++) sf[mf][nf] = (f32x4){0.f, 0.f, 0.f, 0.f};
#pragma unroll
    for (int ks = 0; ks < 2; ks++) {
        short8 aq[2], bk[2];
#pragma unroll
        for (int mf = 0; mf < 2; mf++) {
            int u = mf * 16 + l15;
            int blk = (ks * 4 + g) ^ (u & 7);
            aq[mf] = *(const short8*)&Qs[u * 64 + (blk << 3)];
        }
#pragma unroll
        for (int nf = 0; nf < 2; nf++) {
            int jr = wv * 32 + nf * 16 + l15;
            int blk = (ks * 4 + g) ^ (jr & 7);
            bk[nf] = *(const short8*)&KV[jr * 64 + (blk << 3)];
        }
#pragma unroll
        for (int mf = 0; mf < 2; mf++)
#pragma unroll
            for (int nf = 0; nf < 2; nf++)
                sf[mf][nf] = MFMA_BF16(aq[mf], bk[nf], sf[mf][nf]);
    }

    const unsigned short* vpanel = vbh + ((size_t)b * L + j0) * DM + h * DH;
    short8 vreg[4];
#pragma unroll
    for (int l = 0; l < 4; l++) {
        int f = tid + l * 256;
        int jr = f >> 3, blk = f & 7;
        vreg[l] = *(const short8*)(vpanel + (size_t)jr * DM + blk * 8);
    }

    float sv[2][2][4];
    float mx[2][4];
#pragma unroll
    for (int mf = 0; mf < 2; mf++)
#pragma unroll
        for (int r = 0; r < 4; r++) {
            int u = mf * 16 + g * 4 + r;
            int limv = lims[u];
            float m = -1e30f;
#pragma unroll
            for (int nf = 0; nf < 2; nf++) {
                int jg = j0 + wv * 32 + nf * 16 + l15;
                float s = (jg <= limv) ? sf[mf][nf][r] : -1e30f;
                sv[mf][nf][r] = s;
                m = fmaxf(m, s);
            }
            m = fmaxf(m, __shfl_xor(m, 1, 64));
            m = fmaxf(m, __shfl_xor(m, 2, 64));
            m = fmaxf(m, __shfl_xor(m, 4, 64));
            m = fmaxf(m, __shfl_xor(m, 8, 64));
            mx[mf][r] = m;
        }
    if (l15 == 0) {
#pragma unroll
        for (int mf = 0; mf < 2; mf++)
#pragma unroll
            for (int r = 0; r < 4; r++)
                redm[wv][mf * 16 + g * 4 + r] = mx[mf][r];
    }
    __syncthreads();

    float lmax[2][4], smv[2][4];
#pragma unroll
    for (int mf = 0; mf < 2; mf++)
#pragma unroll
        for (int r = 0; r < 4; r++) {
            int u = mf * 16 + g * 4 + r;
            float m = fmaxf(fmaxf(redm[0][u], redm[1][u]),
                            fmaxf(redm[2][u], redm[3][u]));
            lmax[mf][r] = m;
            bool any = m > -1e29f;
            float sm = 0.f;
#pragma unroll
            for (int nf = 0; nf < 2; nf++) {
                float e = any ? __expf(sv[mf][nf][r] - m) : 0.f;
                sm += e;
                int jr = wv * 32 + nf * 16 + l15;
                Ps[u * 128 + (((jr >> 3) ^ (u & 7)) << 3) + (jr & 7)] = f2bf(e);
            }
            sm += __shfl_xor(sm, 1, 64);
            sm += __shfl_xor(sm, 2, 64);
            sm += __shfl_xor(sm, 4, 64);
            sm += __shfl_xor(sm, 8, 64);
            smv[mf][r] = sm;
        }
    if (l15 == 0) {
#pragma unroll
        for (int mf = 0; mf < 2; mf++)
#pragma unroll
            for (int r = 0; r < 4; r++)
                reds[wv][mf * 16 + g * 4 + r] = smv[mf][r];
    }
#pragma unroll
    for (int l = 0; l < 4; l++) {
        int f = tid + l * 256;
        int jr = f >> 3, blk = f & 7;
        short8 w = vreg[l];
        if ((jr >> 3) & 1) w = __builtin_shufflevector(w, w, 4, 5, 6, 7, 0, 1, 2, 3);
        *(short8*)&KV[jr * 64 + ((blk ^ (jr & 7)) << 3)] = w;
    }
    __syncthreads();

    if (wv == 0 && l15 == 0) {
#pragma unroll
        for (int mf = 0; mf < 2; mf++)
#pragma unroll
            for (int r = 0; r < 4; r++) {
                int u = mf * 16 + g * 4 + r;
                if (u < NTOP) {
                    float ss = reds[0][u] + reds[1][u] + reds[2][u] + reds[3][u];
                    part_m[(bh * NTOP + u) * NCH + c] = lmax[mf][r];
                    part_s[(bh * NTOP + u) * NCH + c] = ss;
                }
            }
    }

    f32x4 of[2];
    of[0] = (f32x4){0.f, 0.f, 0.f, 0.f};
    of[1] = (f32x4){0.f, 0.f, 0.f, 0.f};
    int d = wv * 16 + l15;
#pragma unroll
    for (int ks = 0; ks < 4; ks++) {
        unsigned short va[8];
#pragma unroll
        for (int i = 0; i < 8; i++) {
            int jr = ks * 32 + g * 8 + i;
            int addr = jr * 64 + (((d >> 3) ^ (jr & 7)) << 3)
                     + ((d & 7) ^ (((jr >> 3) & 1) << 2));
            va[i] = KV[addr];
        }
        short8 av;
#pragma unroll
        for (int i = 0; i < 8; i++) av[i] = (short)va[i];
        short8 bp[2];
#pragma unroll
        for (int nf = 0; nf < 2; nf++) {
            int u = nf * 16 + l15;
            int blk = (ks * 4 + g) ^ (u & 7);
            bp[nf] = *(const short8*)&Ps[u * 128 + (blk << 3)];
        }
#pragma unroll
        for (int nf = 0; nf < 2; nf++)
            of[nf] = MFMA_BF16(av, bp[nf], of[nf]);
    }
#pragma unroll
    for (int nf = 0; nf < 2; nf++) {
        int u = nf * 16 + l15;
        if (u < NTOP) {
#pragma unroll
            for (int r = 0; r < 4; r++)
                part_acc[((size_t)(bh * NTOP + u) * NCH + c) * 64 + wv * 16 + g * 4 + r] =
                    of[nf][r];
        }
    }
}

// merge 16 chunk partials per (bh,u); scatter bf16 into pre_h
__global__ __launch_bounds__(256)
void attn_merge_kernel(const float* __restrict__ part_m, const float* __restrict__ part_s,
                       const float* __restrict__ part_acc, const int* __restrict__ mtop,
                       unsigned short* __restrict__ pre_h) {
    int ug = blockIdx.x;
    int bh = blockIdx.y;
    int b = bh >> 3, h = bh & 7;
    int tid = threadIdx.x;
    int u = ug * 4 + (tid >> 6);
    int d = tid & 63;
    int base = (bh * NTOP + u) * NCH;
    float m = -1e30f;
#pragma unroll
    for (int c = 0; c < NCH; c++) m = fmaxf(m, part_m[base + c]);
    float s = 0.f, o = 0.f;
#pragma unroll
    for (int c = 0; c < NCH; c++) {
        float w = __expf(part_m[base + c] - m);
        s += part_s[base + c] * w;
        o = fmaf(part_acc[(size_t)(base + c) * 64 + d], w, o);
    }
    o /= s;
    int iq = mtop[bh * NTOP + u];
    pre_h[((size_t)b * L + iq) * DM + h * DH + d] = f2bf(o);
}

extern "C" void kernel_launch(void* const* d_in, const int* in_sizes, int n_in,
                              void* d_out, int out_size, void* d_ws, size_t ws_size,
                              hipStream_t stream) {
    const float* queries = (const float*)d_in[0];
    const float* keys    = (const float*)d_in[1];
    const float* values  = (const float*)d_in[2];
    const float* pad     = (const float*)d_in[3];
    const float* Wq = (const float*)d_in[4];  const float* bq = (const float*)d_in[5];
    const float* Wk = (const float*)d_in[6];  const float* bk = (const float*)d_in[7];
    const float* Wv = (const float*)d_in[8];  const float* bv = (const float*)d_in[9];
    const float* Wf = (const float*)d_in[10]; const float* bfv = (const float*)d_in[11];
    const float* qlnw = (const float*)d_in[12]; const float* qlnb = (const float*)d_in[13];
    const float* flnw = (const float*)d_in[14]; const float* flnb = (const float*)d_in[15];
    const int* idx = (const int*)d_in[16];

    float* ws = (float*)d_ws;
    const size_t NE = (size_t)B_ * L * DM;   // 8388608
    float* qb    = ws;
    float* kb    = ws + NE;
    unsigned short* vb_h = (unsigned short*)(ws + 2 * NE);   // NE u16
    unsigned short* kb_h = vb_h + NE;                        // NE u16
    unsigned short* qsel = (unsigned short*)(ws + 3 * NE);   // 64*32*64 u16
    int* lim_arr = (int*)(qsel + 64 * 32 * 64);              // 2048 ints
    float* Mbuf  = ws + 4 * NE;                      // 64*2048
    float* denom = Mbuf + (size_t)B_ * H_ * L;       // 8*2048
    float* csum  = denom + (size_t)B_ * L;           // 8*32*512
    int*   mtop  = (int*)(csum + (size_t)B_ * VC * DM);
    unsigned short* bfr = (unsigned short*)(mtop + 2048);
    unsigned short* pre_h = bfr;                     // NE u16
    unsigned short* wts   = bfr + NE;
    unsigned short* wq_h = wts;              unsigned short* wq_l = wts + 262144;
    unsigned short* wk_h = wts + 2 * 262144; unsigned short* wk_l = wts + 3 * 262144;
    unsigned short* wv_h = wts + 4 * 262144; unsigned short* wv_l = wts + 5 * 262144;
    unsigned short* wf_h = wts + 6 * 262144; unsigned short* wf_l = wts + 7 * 262144;

    float* tmp = (float*)d_out;
    unsigned short* lnq_h = (unsigned short*)d_out;   // d_out as bf16 scratch
    unsigned short* lnq_l = lnq_h + NE;
    float* part_m   = tmp;                            // later: attn partials
    float* part_s   = part_m + 64 * NTOP * NCH;
    float* part_acc = part_s + 64 * NTOP * NCH;

    padscan_kernel<<<B_, 256, 0, stream>>>(pad, denom);
    ln_split_kernel<<<B_ * L, 256, 0, stream>>>(queries, qlnw, qlnb, lnq_h, lnq_l);
    dim3 gw(16, 16);
    wsplit_kernel<<<gw, 256, 0, stream>>>(Wq, wq_h, wq_l);
    wsplit_kernel<<<gw, 256, 0, stream>>>(Wk, wk_h, wk_l);
    wsplit_kernel<<<gw, 256, 0, stream>>>(Wv, wv_h, wv_l);
    wsplit_kernel<<<gw, 256, 0, stream>>>(Wf, wf_h, wf_l);

    dim3 gq(4, 128, 3);
    qkv_gemm<<<gq, 256, 0, stream>>>(lnq_h, lnq_l, keys, values,
                                     wq_h, wq_l, wk_h, wk_l, wv_h, wv_l,
                                     bq, bk, bv, qb, kb, kb_h, vb_h);

    sample_m_kernel<<<B_ * L / 4, 256, 0, stream>>>(qb, kb, idx, Mbuf);
    topk_kernel<<<B_ * H_, 64, 0, stream>>>(Mbuf, mtop);
    qprep_kernel<<<64, 256, 0, stream>>>(qb, mtop, pad, qsel, lim_arr);
    dim3 gv(VC, B_);
    vsum_kernel<<<gv, 256, 0, stream>>>(vb_h, csum);
    vavg_kernel<<<gv, 256, 0, stream>>>(vb_h, csum, denom, pre_h);
    dim3 gc(NCH, 64);
    attn_chunk_mfma<<<gc, 256, 0, stream>>>(kb_h, vb_h, qsel, lim_arr,
                                            part_m, part_s, part_acc);
    dim3 gmg(6, 64);
    attn_merge_kernel<<<gmg, 256, 0, stream>>>(part_m, part_s, part_acc, mtop, pre_h);
    dim3 gg(4, 128);
    gemm_mfma<1, 0, 0><<<gg, 256, 0, stream>>>(pre_h, nullptr, nullptr, wf_h, wf_l, bfv, (float*)d_out, nullptr);
    ln_kernel<<<B_ * L, 256, 0, stream>>>((float*)d_out, flnw, flnb, (float*)d_out);
}

// Round 17
// 224.769 us; speedup vs baseline: 1.1337x; 1.1337x over previous
//
#include <hip/hip_runtime.h>
#include <math.h>

#define L 2048
#define DM 512
#define B_ 8
#define H_ 8
#define DH 64
#define SK 24
#define NTOP 24
#define CHUNK 128
#define NCH (L / CHUNK)   // 16
#define VC 32             // vavg chunks
#define VR 64             // rows per vavg chunk
#define ABUF 4096         // u16 per LDS gemm buffer (128 rows x 32 k, swizzled, no pad)

typedef __attribute__((ext_vector_type(8))) short short8;
typedef __attribute__((ext_vector_type(8))) __bf16 bf16x8;
typedef __attribute__((ext_vector_type(4))) float f32x4;

__device__ inline unsigned short f2bf(float x) {
    unsigned u = __float_as_uint(x);
    unsigned r = (u + 0x7FFFu + ((u >> 16) & 1u)) >> 16;
    return (unsigned short)r;
}
__device__ inline float bf2f(unsigned short h) {
    return __uint_as_float(((unsigned)h) << 16);
}

__device__ inline f32x4 MFMA_BF16(short8 a, short8 b, f32x4 c) {
    return __builtin_amdgcn_mfma_f32_16x16x32_bf16(
        __builtin_bit_cast(bf16x8, a), __builtin_bit_cast(bf16x8, b), c, 0, 0, 0);
}

// convert 8 f32 (two float4) to bf16 hi (and optionally lo) short8
template<bool WANTL>
__device__ inline void cvt8(const float4& x, const float4& y, short8& h, short8& l) {
    float v0 = x.x, v1 = x.y, v2 = x.z, v3 = x.w;
    float v4 = y.x, v5 = y.y, v6 = y.z, v7 = y.w;
    unsigned short h0 = f2bf(v0), h1 = f2bf(v1), h2 = f2bf(v2), h3 = f2bf(v3);
    unsigned short h4 = f2bf(v4), h5 = f2bf(v5), h6 = f2bf(v6), h7 = f2bf(v7);
    h[0] = (short)h0; h[1] = (short)h1; h[2] = (short)h2; h[3] = (short)h3;
    h[4] = (short)h4; h[5] = (short)h5; h[6] = (short)h6; h[7] = (short)h7;
    if (WANTL) {
        l[0] = (short)f2bf(v0 - bf2f(h0)); l[1] = (short)f2bf(v1 - bf2f(h1));
        l[2] = (short)f2bf(v2 - bf2f(h2)); l[3] = (short)f2bf(v3 - bf2f(h3));
        l[4] = (short)f2bf(v4 - bf2f(h4)); l[5] = (short)f2bf(v5 - bf2f(h5));
        l[6] = (short)f2bf(v6 - bf2f(h6)); l[7] = (short)f2bf(v7 - bf2f(h7));
    }
}

// swizzled LDS address: conflict-free stores, 2-way (free) reads; no padding.
// (verified r12/r13: SQ_LDS_BANK_CONFLICT == 0)
__device__ inline int lds_addr(int row, int kblk) {
    return row * 32 + ((kblk ^ ((row >> 1) & 3)) << 3);
}

// ---------------- reduce helpers ----------------
__device__ inline float waveReduceSum(float v) {
    for (int o = 32; o > 0; o >>= 1) v += __shfl_down(v, o, 64);
    return v;
}

// ---------------- fused preprocessing: ln_split | wsplit x4 | padscan ----------------
// branch is blockIdx-uniform; shared memory aliased via one max-size buffer.
__global__ __launch_bounds__(256)
void prep_kernel(const float* __restrict__ queries,
                 const float* __restrict__ qlnw, const float* __restrict__ qlnb,
                 unsigned short* __restrict__ lnq_h, unsigned short* __restrict__ lnq_l,
                 const float* __restrict__ Wq, const float* __restrict__ Wk,
                 const float* __restrict__ Wv, const float* __restrict__ Wf,
                 unsigned short* __restrict__ wts,
                 const float* __restrict__ pad, float* __restrict__ denom) {
    __shared__ float shmem[32 * 33];
    int bid = blockIdx.x;
    int tid = threadIdx.x;
    if (bid < 16384) {
        // ---- ln_split (row = bid) ----
        int row = bid;
        const float* xr = queries + (size_t)row * DM;
        float2 v = *(const float2*)(xr + tid * 2);
        float s = v.x + v.y;
        float sq = v.x * v.x + v.y * v.y;
        float* red = shmem;
        float wsu = waveReduceSum(s);
        float wq = waveReduceSum(sq);
        int wid = tid >> 6, lane = tid & 63;
        if (lane == 0) { red[wid] = wsu; red[4 + wid] = wq; }
        __syncthreads();
        float tot = red[0] + red[1] + red[2] + red[3];
        float totq = red[4] + red[5] + red[6] + red[7];
        float mean = tot * (1.0f / DM);
        float var = totq * (1.0f / DM) - mean * mean;
        float inv = rsqrtf(var + 1e-8f);
        float w0 = qlnw[tid * 2], w1 = qlnw[tid * 2 + 1];
        float b0 = qlnb[tid * 2], b1 = qlnb[tid * 2 + 1];
        float o0 = w0 * (v.x - mean) * inv + b0;
        float o1 = w1 * (v.y - mean) * inv + b1;
        ushort2 hh, ll;
        hh.x = f2bf(o0); ll.x = f2bf(o0 - bf2f(hh.x));
        hh.y = f2bf(o1); ll.y = f2bf(o1 - bf2f(hh.y));
        *(ushort2*)(lnq_h + (size_t)row * DM + tid * 2) = hh;
        *(ushort2*)(lnq_l + (size_t)row * DM + tid * 2) = ll;
    } else if (bid < 16384 + 1024) {
        // ---- wsplit (weight w, 32x32 tile) ----
        int idx = bid - 16384;
        int w = idx >> 8;
        int t256 = idx & 255;
        int n0 = (t256 & 15) * 32, k0 = (t256 >> 4) * 32;
        const float* W = (w == 0) ? Wq : (w == 1) ? Wk : (w == 2) ? Wv : Wf;
        unsigned short* th = wts + (size_t)w * 2 * 262144;
        unsigned short* tl = th + 262144;
        float (*ts)[33] = (float(*)[33])shmem;
        int r = tid >> 3, c = (tid & 7) * 4;
        float4 v = *(const float4*)(W + (size_t)(k0 + r) * 512 + n0 + c);
        ts[r][c] = v.x; ts[r][c + 1] = v.y; ts[r][c + 2] = v.z; ts[r][c + 3] = v.w;
        __syncthreads();
        float a0 = ts[c + 0][r], a1 = ts[c + 1][r], a2 = ts[c + 2][r], a3 = ts[c + 3][r];
        ushort4 h, l;
        h.x = f2bf(a0); l.x = f2bf(a0 - bf2f(h.x));
        h.y = f2bf(a1); l.y = f2bf(a1 - bf2f(h.y));
        h.z = f2bf(a2); l.z = f2bf(a2 - bf2f(h.z));
        h.w = f2bf(a3); l.w = f2bf(a3 - bf2f(h.w));
        *(ushort4*)(th + (size_t)(n0 + r) * 512 + k0 + c) = h;
        *(ushort4*)(tl + (size_t)(n0 + r) * 512 + k0 + c) = l;
    } else {
        // ---- padscan (b = bid - 17408) ----
        int b = bid - (16384 + 1024);
        float* tot = shmem;
        const float* p = pad + (size_t)b * L;
        float loc[8];
        float s = 0.f;
#pragma unroll
        for (int u = 0; u < 8; u++) { s += p[tid * 8 + u]; loc[u] = s; }
        tot[tid] = s;
        __syncthreads();
        for (int off = 1; off < 256; off <<= 1) {
            float add = (tid >= off) ? tot[tid - off] : 0.f;
            __syncthreads();
            tot[tid] += add;
            __syncthreads();
        }
        float excl = tot[tid] - s;
#pragma unroll
        for (int u = 0; u < 8; u++) denom[(size_t)b * L + tid * 8 + u] = excl + loc[u];
    }
}

// ---------------- MFMA split GEMM body, 128x128 tile (r15 best: 242us total) ----
// single buffer, 2-barrier schedule, XOR-swizzled no-pad layout (0 conflicts).
// TERMS: 3 = Ah*Bh + Ah*Bl + Al*Bh, 2 = Ah*Bh + Ah*Bl, 1 = Ah*Bh
// OMODE: 0 = f32 only, 1 = f32 + bf16 mirror, 2 = bf16 only
// ACVT : 0 = A pre-split bf16 (Ah/Al), 1 = A f32 (Af), hi/lo in-register
template<int TERMS, int OMODE, int ACVT>
__device__ __forceinline__
void gemm_body(unsigned short* smem,
               const unsigned short* __restrict__ Ah, const unsigned short* __restrict__ Al,
               const float* __restrict__ Af,
               const unsigned short* __restrict__ Bh, const unsigned short* __restrict__ Bl,
               const float* __restrict__ bias, float* __restrict__ C,
               unsigned short* __restrict__ Ch, int orig) {
    unsigned short* sAh = smem;
    unsigned short* sAl = smem + ABUF;                            // TERMS==3 only
    unsigned short* sBh = smem + (TERMS == 3 ? 2 : 1) * ABUF;
    unsigned short* sBl = sBh + ABUF;                             // TERMS>=2 only

    int j = (orig & 7) * 64 + (orig >> 3);
    int n0 = (j & 3) * 128, m0 = (j >> 2) * 128;

    int tid = threadIdx.x;
    int lane = tid & 63, wv = tid >> 6;
    int wr = wv >> 1, wc = wv & 1;
    int lrow = lane & 15, g = lane >> 4;

    int f0 = tid, f1 = tid + 256;
    int row0 = f0 >> 2, k0b = f0 & 3;
    int row1 = f1 >> 2, k1b = f1 & 3;
    int sa0 = lds_addr(row0, k0b), sa1 = lds_addr(row1, k1b);
    int c0 = k0b * 8, c1 = k1b * 8;

    f32x4 acc[4][4];
#pragma unroll
    for (int mf = 0; mf < 4; mf++)
#pragma unroll
        for (int nf = 0; nf < 4; nf++) acc[mf][nf] = (f32x4){0.f, 0.f, 0.f, 0.f};

    short8 rAh0, rAh1, rAl0, rAl1, rBh0, rBh1, rBl0, rBl1;
    float4 fA00, fA01, fA10, fA11;

    auto LOAD = [&](int kt) {
        int k0 = kt * 32;
        if (ACVT) {
            fA00 = *(const float4*)(Af + (size_t)(m0 + row0) * 512 + k0 + c0);
            fA01 = *(const float4*)(Af + (size_t)(m0 + row0) * 512 + k0 + c0 + 4);
            fA10 = *(const float4*)(Af + (size_t)(m0 + row1) * 512 + k0 + c1);
            fA11 = *(const float4*)(Af + (size_t)(m0 + row1) * 512 + k0 + c1 + 4);
        } else {
            rAh0 = *(const short8*)(Ah + (size_t)(m0 + row0) * 512 + k0 + c0);
            rAh1 = *(const short8*)(Ah + (size_t)(m0 + row1) * 512 + k0 + c1);
            if (TERMS == 3) {
                rAl0 = *(const short8*)(Al + (size_t)(m0 + row0) * 512 + k0 + c0);
                rAl1 = *(const short8*)(Al + (size_t)(m0 + row1) * 512 + k0 + c1);
            }
        }
        rBh0 = *(const short8*)(Bh + (size_t)(n0 + row0) * 512 + k0 + c0);
        rBh1 = *(const short8*)(Bh + (size_t)(n0 + row1) * 512 + k0 + c1);
        if (TERMS >= 2) {
            rBl0 = *(const short8*)(Bl + (size_t)(n0 + row0) * 512 + k0 + c0);
            rBl1 = *(const short8*)(Bl + (size_t)(n0 + row1) * 512 + k0 + c1);
        }
    };
    auto STORE = [&]() {
        if (ACVT) {
            cvt8<TERMS == 3>(fA00, fA01, rAh0, rAl0);
            cvt8<TERMS == 3>(fA10, fA11, rAh1, rAl1);
        }
        *(short8*)&sAh[sa0] = rAh0;
        *(short8*)&sAh[sa1] = rAh1;
        if (TERMS == 3) {
            *(short8*)&sAl[sa0] = rAl0;
            *(short8*)&sAl[sa1] = rAl1;
        }
        *(short8*)&sBh[sa0] = rBh0;
        *(short8*)&sBh[sa1] = rBh1;
        if (TERMS >= 2) {
            *(short8*)&sBl[sa0] = rBl0;
            *(short8*)&sBl[sa1] = rBl1;
        }
    };

    int ra = wr * 64 + lrow;
    int rb = wc * 64 + lrow;
    int abase = ra * 32 + ((g ^ ((ra >> 1) & 3)) << 3);
    int bbase = rb * 32 + ((g ^ ((rb >> 1) & 3)) << 3);

    LOAD(0);
    for (int kt = 0; kt < 16; kt++) {
        STORE();
        __syncthreads();
        if (kt < 15) LOAD(kt + 1);
        short8 ah[4], al[4], bh[4], bl[4];
#pragma unroll
        for (int mf = 0; mf < 4; mf++) {
            ah[mf] = *(const short8*)&sAh[abase + mf * 512];
            if (TERMS == 3) al[mf] = *(const short8*)&sAl[abase + mf * 512];
        }
#pragma unroll
        for (int nf = 0; nf < 4; nf++) {
            bh[nf] = *(const short8*)&sBh[bbase + nf * 512];
            if (TERMS >= 2) bl[nf] = *(const short8*)&sBl[bbase + nf * 512];
        }
#pragma unroll
        for (int mf = 0; mf < 4; mf++)
#pragma unroll
            for (int nf = 0; nf < 4; nf++) {
                acc[mf][nf] = MFMA_BF16(ah[mf], bh[nf], acc[mf][nf]);
                if (TERMS >= 2) acc[mf][nf] = MFMA_BF16(ah[mf], bl[nf], acc[mf][nf]);
                if (TERMS == 3) acc[mf][nf] = MFMA_BF16(al[mf], bh[nf], acc[mf][nf]);
            }
        __syncthreads();
    }

    int crow0 = m0 + wr * 64 + (lane >> 4) * 4;
    int ccol0 = n0 + wc * 64 + lrow;
    float bb[4];
#pragma unroll
    for (int nf = 0; nf < 4; nf++) bb[nf] = bias[ccol0 + nf * 16];
#pragma unroll
    for (int mf = 0; mf < 4; mf++)
#pragma unroll
        for (int nf = 0; nf < 4; nf++)
#pragma unroll
            for (int r = 0; r < 4; r++) {
                float val = acc[mf][nf][r] + bb[nf];
                size_t idx = (size_t)(crow0 + mf * 16 + r) * 512 + ccol0 + nf * 16;
                if (OMODE != 2) C[idx] = val;
                if (OMODE != 0) Ch[idx] = f2bf(val);
            }
}

// fused Q/K/V GEMM (blockIdx.z selects sub-GEMM); 32KB LDS
__global__ __launch_bounds__(256, 2)
void qkv_gemm(const unsigned short* __restrict__ lnq_h, const unsigned short* __restrict__ lnq_l,
              const float* __restrict__ keys, const float* __restrict__ values,
              const unsigned short* __restrict__ wq_h, const unsigned short* __restrict__ wq_l,
              const unsigned short* __restrict__ wk_h, const unsigned short* __restrict__ wk_l,
              const unsigned short* __restrict__ wv_h, const unsigned short* __restrict__ wv_l,
              const float* __restrict__ bq, const float* __restrict__ bk, const float* __restrict__ bv,
              float* __restrict__ qb, float* __restrict__ kb,
              unsigned short* __restrict__ kb_h, unsigned short* __restrict__ vb_h) {
    __shared__ __align__(16) unsigned short smem[4 * ABUF];  // 32KB (single-buf, 3-term)
    int orig = blockIdx.x + 4 * blockIdx.y;
    if (blockIdx.z == 0)
        gemm_body<3, 0, 0>(smem, lnq_h, lnq_l, nullptr, wq_h, wq_l, bq, qb, nullptr, orig);
    else if (blockIdx.z == 1)
        gemm_body<3, 1, 1>(smem, nullptr, nullptr, keys, wk_h, wk_l, bk, kb, kb_h, orig);
    else
        gemm_body<1, 2, 1>(smem, nullptr, nullptr, values, wv_h, wv_l, bv, nullptr, vb_h, orig);
}

// standalone (final F-GEMM, 1-term -> 16KB LDS)
template<int TERMS, int OMODE, int ACVT>
__global__ __launch_bounds__(256, 2)
void gemm_mfma(const unsigned short* __restrict__ Ah, const unsigned short* __restrict__ Al,
               const float* __restrict__ Af,
               const unsigned short* __restrict__ Bh, const unsigned short* __restrict__ Bl,
               const float* __restrict__ bias, float* __restrict__ C,
               unsigned short* __restrict__ Ch) {
    __shared__ __align__(16) unsigned short smem[(TERMS == 3 ? 4 : (TERMS == 2 ? 3 : 2)) * ABUF];
    int orig = blockIdx.x + 4 * blockIdx.y;
    gemm_body<TERMS, OMODE, ACVT>(smem, Ah, Al, Af, Bh, Bl, bias, C, Ch, orig);
}

// ---------------- fused: sample_m | vsum ----------------
__global__ __launch_bounds__(256)
void sm_vsum_kernel(const float* __restrict__ q, const float* __restrict__ k,
                    const int* __restrict__ idx, float* __restrict__ M,
                    const unsigned short* __restrict__ vh, float* __restrict__ csum) {
    int bid = blockIdx.x;
    if (bid < 4096) {
        // ---- sample_m: deferred reduction, independent gathers, XCD-pinned ----
        int b = bid & 7;
        int ig = bid >> 3;
        int wv = threadIdx.x >> 6, lane = threadIdx.x & 63;
        int i = ig * 4 + wv;
        const float* qrow = q + ((size_t)b * L + i) * DM + lane * 8;
        float4 q0 = *(const float4*)qrow;
        float4 q1 = *(const float4*)(qrow + 4);
        int myidx = 0;
        if (lane < SK) myidx = idx[i * SK + lane];
        float sj[SK];
#pragma unroll
        for (int j = 0; j < SK; j++) {
            int row = __shfl(myidx, j, 64);
            const float* kp = k + ((size_t)b * L + row) * DM + lane * 8;
            float4 k0 = *(const float4*)kp;
            float4 k1 = *(const float4*)(kp + 4);
            sj[j] = q0.x * k0.x + q0.y * k0.y + q0.z * k0.z + q0.w * k0.w
                  + q1.x * k1.x + q1.y * k1.y + q1.z * k1.z + q1.w * k1.w;
        }
        float mx = -1e30f, sm = 0.f;
#pragma unroll
        for (int j = 0; j < SK; j++) {
            float s = sj[j];
            s += __shfl_xor(s, 1, 64);
            s += __shfl_xor(s, 2, 64);
            s += __shfl_xor(s, 4, 64);
            mx = fmaxf(mx, s);
            sm += s;
        }
        if ((lane & 7) == 0) {
            int h = lane >> 3;
            M[((size_t)b * H_ + h) * L + i] = mx - sm * (1.0f / L);
        }
    } else {
        // ---- vsum ----
        int t = bid - 4096;
        int c = t & (VC - 1), b = t >> 5;
        int d2 = threadIdx.x;
        size_t base = ((size_t)b * L + c * VR) * DM + d2 * 2;
        float a0 = 0.f, a1 = 0.f;
        for (int tt = 0; tt < VR; tt++) {
            unsigned v = *(const unsigned*)(vh + base + (size_t)tt * DM);
            a0 += bf2f((unsigned short)(v & 0xffff));
            a1 += bf2f((unsigned short)(v >> 16));
        }
        float2 st = {a0, a1};
        *(float2*)(csum + ((size_t)b * VC + c) * DM + d2 * 2) = st;
    }
}

// ---------------- fused: topk | vavg ----------------
__global__ __launch_bounds__(256)
void topk_vavg_kernel(const float* __restrict__ M, int* __restrict__ mtop,
                      const unsigned short* __restrict__ vh, const float* __restrict__ csum,
                      const float* __restrict__ denom, unsigned short* __restrict__ out_h) {
    int bid = blockIdx.x;
    if (bid < 64) {
        // ---- topk: one wave, register-resident (threads 64..255 idle) ----
        if (threadIdx.x >= 64) return;
        int bh = bid;
        int lane = threadIdx.x;
        const float* Mr = M + (size_t)bh * L;
        float m[32];
#pragma unroll
        for (int r = 0; r < 32; r++) m[r] = Mr[r * 64 + lane];
        for (int it = 0; it < NTOP; it++) {
            float bv = -1e30f; int br = 0;
#pragma unroll
            for (int r = 0; r < 32; r++) {
                bool better = m[r] > bv;   // strict > keeps lowest r on ties
                br = better ? r : br;
                bv = better ? m[r] : bv;
            }
            int bt = (br << 6) | lane;
#pragma unroll
            for (int o = 1; o < 64; o <<= 1) {
                float ov = __shfl_xor(bv, o, 64);
                int ot = __shfl_xor(bt, o, 64);
                bool take = (ov > bv) || (ov == bv && ot < bt);
                bv = take ? ov : bv;
                bt = take ? ot : bt;
            }
            if (lane == 0) mtop[bh * NTOP + it] = bt;
            int rwin = bt >> 6;
            bool mine = (bt & 63) == lane;
#pragma unroll
            for (int r = 0; r < 32; r++)
                if (mine && (r == rwin)) m[r] = -1e30f;
        }
    } else {
        // ---- vavg ----
        int t = bid - 64;
        int c = t & (VC - 1), b = t >> 5;
        int d2 = threadIdx.x;
        float a0 = 0.f, a1 = 0.f;
        for (int cc = 0; cc < c; cc++) {
            float2 tt = *(const float2*)(csum + ((size_t)b * VC + cc) * DM + d2 * 2);
            a0 += tt.x; a1 += tt.y;
        }
        size_t base = ((size_t)b * L + c * VR) * DM + d2 * 2;
        for (int tt = 0; tt < VR; tt++) {
            unsigned v = *(const unsigned*)(vh + base + (size_t)tt * DM);
            a0 += bf2f((unsigned short)(v & 0xffff));
            a1 += bf2f((unsigned short)(v >> 16));
            float dn = denom[(size_t)b * L + c * VR + tt] + 1e-12f;
            unsigned o = (unsigned)f2bf(a0 / dn) | ((unsigned)f2bf(a1 / dn) << 16);
            *(unsigned*)(out_h + base + (size_t)tt * DM) = o;
        }
    }
}

// ---------------- Q gather + pre-scale + lim prep (parallel) ----------------
__global__ __launch_bounds__(256)
void qprep_kernel(const float* __restrict__ qb, const int* __restrict__ mtop,
                  const float* __restrict__ pad, unsigned short* __restrict__ qsel,
                  int* __restrict__ lim_arr) {
    int bh = blockIdx.x; int b = bh >> 3, h = bh & 7;
    int tid = threadIdx.x;
#pragma unroll
    for (int l = 0; l < 2; l++) {
        int f = tid + l * 256;        // 0..511
        int u = f >> 4, seg = (f & 15) * 4;
        ushort4 o;
        if (u < NTOP) {
            int iq = mtop[bh * NTOP + u];
            bool ok = pad[(size_t)b * L + iq] != 0.f;
            float sc = ok ? 0.044194173824159216f : 0.f;
            float4 qv = *(const float4*)(qb + ((size_t)b * L + iq) * DM + h * DH + seg);
            o.x = f2bf(qv.x * sc); o.y = f2bf(qv.y * sc);
            o.z = f2bf(qv.z * sc); o.w = f2bf(qv.w * sc);
            if (seg == 0) lim_arr[bh * 32 + u] = ok ? iq : (L - 1);
        } else {
            o.x = o.y = o.z = o.w = 0;
            if (seg == 0) lim_arr[bh * 32 + u] = -1;
        }
        *(ushort4*)(qsel + ((size_t)bh * 32 + u) * 64 + seg) = o;
    }
}

// ---------------- MFMA split-chunk sparse attention ----------------
__global__ __launch_bounds__(256)
void attn_chunk_mfma(const unsigned short* __restrict__ kbh,
                     const unsigned short* __restrict__ vbh,
                     const unsigned short* __restrict__ qsel,
                     const int* __restrict__ lim_arr,
                     float* __restrict__ part_m, float* __restrict__ part_s,
                     float* __restrict__ part_acc) {
    int c = blockIdx.x, bh = blockIdx.y;
    int b = bh >> 3, h = bh & 7;
    int j0 = c * CHUNK;
    __shared__ __align__(16) unsigned short KV[128 * 64];
    __shared__ __align__(16) unsigned short Ps[32 * 128];
    __shared__ __align__(16) unsigned short Qs[32 * 64];
    __shared__ float redm[4][32];
    __shared__ float reds[4][32];
    __shared__ int lims[32];

    int tid = threadIdx.x;
    int wv = tid >> 6, lane = tid & 63;
    int l15 = lane & 15, g = lane >> 4;

    const unsigned short* kpanel = kbh + ((size_t)b * L + j0) * DM + h * DH;
    short8 kreg[4];
#pragma unroll
    for (int l = 0; l < 4; l++) {
        int f = tid + l * 256;
        int jr = f >> 3, blk = f & 7;
        kreg[l] = *(const short8*)(kpanel + (size_t)jr * DM + blk * 8);
    }
    {
        int u = tid >> 3, blk = tid & 7;
        short8 qreg = *(const short8*)(qsel + ((size_t)bh * 32 + u) * 64 + blk * 8);
        *(short8*)&Qs[u * 64 + (((blk ^ (u & 7))) << 3)] = qreg;
    }
#pragma unroll
    for (int l = 0; l < 4; l++) {
        int f = tid + l * 256;
        int jr = f >> 3, blk = f & 7;
        *(short8*)&KV[jr * 64 + ((blk ^ (jr & 7)) << 3)] = kreg[l];
    }
    if (tid < 32) lims[tid] = lim_arr[bh * 32 + tid];
    __syncthreads();

    f32x4 sf[2][2];
#pragma unroll
    for (int mf = 0; mf < 2; mf++)
#pragma unroll
        for (int nf = 0; nf < 2; nf++) sf[mf][nf] = (f32x4){0.f, 0.f, 0.f, 0.f};
#pragma unroll
    for (int ks = 0; ks < 2; ks++) {
        short8 aq[2], bk[2];
#pragma unroll
        for (int mf = 0; mf < 2; mf++) {
            int u = mf * 16 + l15;
            int blk = (ks * 4 + g) ^ (u & 7);
            aq[mf] = *(const short8*)&Qs[u * 64 + (blk << 3)];
        }
#pragma unroll
        for (int nf = 0; nf < 2; nf++) {
            int jr = wv * 32 + nf * 16 + l15;
            int blk = (ks * 4 + g) ^ (jr & 7);
            bk[nf] = *(const short8*)&KV[jr * 64 + (blk << 3)];
        }
#pragma unroll
        for (int mf = 0; mf < 2; mf++)
#pragma unroll
            for (int nf = 0; nf < 2; nf++)
                sf[mf][nf] = MFMA_BF16(aq[mf], bk[nf], sf[mf][nf]);
    }

    const unsigned short* vpanel = vbh + ((size_t)b * L + j0) * DM + h * DH;
    short8 vreg[4];
#pragma unroll
    for (int l = 0; l < 4; l++) {
        int f = tid + l * 256;
        int jr = f >> 3, blk = f & 7;
        vreg[l] = *(const short8*)(vpanel + (size_t)jr * DM + blk * 8);
    }

    float sv[2][2][4];
    float mx[2][4];
#pragma unroll
    for (int mf = 0; mf < 2; mf++)
#pragma unroll
        for (int r = 0; r < 4; r++) {
            int u = mf * 16 + g * 4 + r;
            int limv = lims[u];
            float m = -1e30f;
#pragma unroll
            for (int nf = 0; nf < 2; nf++) {
                int jg = j0 + wv * 32 + nf * 16 + l15;
                float s = (jg <= limv) ? sf[mf][nf][r] : -1e30f;
                sv[mf][nf][r] = s;
                m = fmaxf(m, s);
            }
            m = fmaxf(m, __shfl_xor(m, 1, 64));
            m = fmaxf(m, __shfl_xor(m, 2, 64));
            m = fmaxf(m, __shfl_xor(m, 4, 64));
            m = fmaxf(m, __shfl_xor(m, 8, 64));
            mx[mf][r] = m;
        }
    if (l15 == 0) {
#pragma unroll
        for (int mf = 0; mf < 2; mf++)
#pragma unroll
            for (int r = 0; r < 4; r++)
                redm[wv][mf * 16 + g * 4 + r] = mx[mf][r];
    }
    __syncthreads();

    float lmax[2][4], smv[2][4];
#pragma unroll
    for (int mf = 0; mf < 2; mf++)
#pragma unroll
        for (int r = 0; r < 4; r++) {
            int u = mf * 16 + g * 4 + r;
            float m = fmaxf(fmaxf(redm[0][u], redm[1][u]),
                            fmaxf(redm[2][u], redm[3][u]));
            lmax[mf][r] = m;
            bool any = m > -1e29f;
            float sm = 0.f;
#pragma unroll
            for (int nf = 0; nf < 2; nf++) {
                float e = any ? __expf(sv[mf][nf][r] - m) : 0.f;
                sm += e;
                int jr = wv * 32 + nf * 16 + l15;
                Ps[u * 128 + (((jr >> 3) ^ (u & 7)) << 3) + (jr & 7)] = f2bf(e);
            }
            sm += __shfl_xor(sm, 1, 64);
            sm += __shfl_xor(sm, 2, 64);
            sm += __shfl_xor(sm, 4, 64);
            sm += __shfl_xor(sm, 8, 64);
            smv[mf][r] = sm;
        }
    if (l15 == 0) {
#pragma unroll
        for (int mf = 0; mf < 2; mf++)
#pragma unroll
            for (int r = 0; r < 4; r++)
                reds[wv][mf * 16 + g * 4 + r] = smv[mf][r];
    }
#pragma unroll
    for (int l = 0; l < 4; l++) {
        int f = tid + l * 256;
        int jr = f >> 3, blk = f & 7;
        short8 w = vreg[l];
        if ((jr >> 3) & 1) w = __builtin_shufflevector(w, w, 4, 5, 6, 7, 0, 1, 2, 3);
        *(short8*)&KV[jr * 64 + ((blk ^ (jr & 7)) << 3)] = w;
    }
    __syncthreads();

    if (wv == 0 && l15 == 0) {
#pragma unroll
        for (int mf = 0; mf < 2; mf++)
#pragma unroll
            for (int r = 0; r < 4; r++) {
                int u = mf * 16 + g * 4 + r;
                if (u < NTOP) {
                    float ss = reds[0][u] + reds[1][u] + reds[2][u] + reds[3][u];
                    part_m[(bh * NTOP + u) * NCH + c] = lmax[mf][r];
                    part_s[(bh * NTOP + u) * NCH + c] = ss;
                }
            }
    }

    f32x4 of[2];
    of[0] = (f32x4){0.f, 0.f, 0.f, 0.f};
    of[1] = (f32x4){0.f, 0.f, 0.f, 0.f};
    int d = wv * 16 + l15;
#pragma unroll
    for (int ks = 0; ks < 4; ks++) {
        unsigned short va[8];
#pragma unroll
        for (int i = 0; i < 8; i++) {
            int jr = ks * 32 + g * 8 + i;
            int addr = jr * 64 + (((d >> 3) ^ (jr & 7)) << 3)
                     + ((d & 7) ^ (((jr >> 3) & 1) << 2));
            va[i] = KV[addr];
        }
        short8 av;
#pragma unroll
        for (int i = 0; i < 8; i++) av[i] = (short)va[i];
        short8 bp[2];
#pragma unroll
        for (int nf = 0; nf < 2; nf++) {
            int u = nf * 16 + l15;
            int blk = (ks * 4 + g) ^ (u & 7);
            bp[nf] = *(const short8*)&Ps[u * 128 + (blk << 3)];
        }
#pragma unroll
        for (int nf = 0; nf < 2; nf++)
            of[nf] = MFMA_BF16(av, bp[nf], of[nf]);
    }
#pragma unroll
    for (int nf = 0; nf < 2; nf++) {
        int u = nf * 16 + l15;
        if (u < NTOP) {
#pragma unroll
            for (int r = 0; r < 4; r++)
                part_acc[((size_t)(bh * NTOP + u) * NCH + c) * 64 + wv * 16 + g * 4 + r] =
                    of[nf][r];
        }
    }
}

// merge 16 chunk partials per (bh,u); scatter bf16 into pre_h
__global__ __launch_bounds__(256)
void attn_merge_kernel(const float* __restrict__ part_m, const float* __restrict__ part_s,
                       const float* __restrict__ part_acc, const int* __restrict__ mtop,
                       unsigned short* __restrict__ pre_h) {
    int ug = blockIdx.x;
    int bh = blockIdx.y;
    int b = bh >> 3, h = bh & 7;
    int tid = threadIdx.x;
    int u = ug * 4 + (tid >> 6);
    int d = tid & 63;
    int base = (bh * NTOP + u) * NCH;
    float m = -1e30f;
#pragma unroll
    for (int c = 0; c < NCH; c++) m = fmaxf(m, part_m[base + c]);
    float s = 0.f, o = 0.f;
#pragma unroll
    for (int c = 0; c < NCH; c++) {
        float w = __expf(part_m[base + c] - m);
        s += part_s[base + c] * w;
        o = fmaf(part_acc[(size_t)(base + c) * 64 + d], w, o);
    }
    o /= s;
    int iq = mtop[bh * NTOP + u];
    pre_h[((size_t)b * L + iq) * DM + h * DH + d] = f2bf(o);
}

// ---------------- final LayerNorm (row-wise, 512 cols) ----------------
__global__ __launch_bounds__(256)
void ln_kernel(const float* __restrict__ x, const float* __restrict__ w,
               const float* __restrict__ bvec, float* __restrict__ out) {
    int row = blockIdx.x;
    const float* xr = x + (size_t)row * DM;
    float* orow = out + (size_t)row * DM;
    int tid = threadIdx.x;
    float2 v = *(const float2*)(xr + tid * 2);
    float s = v.x + v.y;
    float sq = v.x * v.x + v.y * v.y;
    __shared__ float red[8];
    float ws = waveReduceSum(s);
    float wq = waveReduceSum(sq);
    int wid = tid >> 6, lane = tid & 63;
    if (lane == 0) { red[wid] = ws; red[4 + wid] = wq; }
    __syncthreads();
    float tot = red[0] + red[1] + red[2] + red[3];
    float totq = red[4] + red[5] + red[6] + red[7];
    float mean = tot * (1.0f / DM);
    float var = totq * (1.0f / DM) - mean * mean;
    float inv = rsqrtf(var + 1e-8f);
    float w0 = w[tid * 2], w1 = w[tid * 2 + 1];
    float b0 = bvec[tid * 2], b1 = bvec[tid * 2 + 1];
    float2 o;
    o.x = w0 * (v.x - mean) * inv + b0;
    o.y = w1 * (v.y - mean) * inv + b1;
    *(float2*)(orow + tid * 2) = o;
}

extern "C" void kernel_launch(void* const* d_in, const int* in_sizes, int n_in,
                              void* d_out, int out_size, void* d_ws, size_t ws_size,
                              hipStream_t stream) {
    const float* queries = (const float*)d_in[0];
    const float* keys    = (const float*)d_in[1];
    const float* values  = (const float*)d_in[2];
    const float* pad     = (const float*)d_in[3];
    const float* Wq = (const float*)d_in[4];  const float* bq = (const float*)d_in[5];
    const float* Wk = (const float*)d_in[6];  const float* bk = (const float*)d_in[7];
    const float* Wv = (const float*)d_in[8];  const float* bv = (const float*)d_in[9];
    const float* Wf = (const float*)d_in[10]; const float* bfv = (const float*)d_in[11];
    const float* qlnw = (const float*)d_in[12]; const float* qlnb = (const float*)d_in[13];
    const float* flnw = (const float*)d_in[14]; const float* flnb = (const float*)d_in[15];
    const int* idx = (const int*)d_in[16];

    float* ws = (float*)d_ws;
    const size_t NE = (size_t)B_ * L * DM;   // 8388608
    float* qb    = ws;
    float* kb    = ws + NE;
    unsigned short* vb_h = (unsigned short*)(ws + 2 * NE);   // NE u16
    unsigned short* kb_h = vb_h + NE;                        // NE u16
    unsigned short* qsel = (unsigned short*)(ws + 3 * NE);   // 64*32*64 u16
    int* lim_arr = (int*)(qsel + 64 * 32 * 64);              // 2048 ints
    float* Mbuf  = ws + 4 * NE;                      // 64*2048
    float* denom = Mbuf + (size_t)B_ * H_ * L;       // 8*2048
    float* csum  = denom + (size_t)B_ * L;           // 8*32*512
    int*   mtop  = (int*)(csum + (size_t)B_ * VC * DM);
    unsigned short* bfr = (unsigned short*)(mtop + 2048);
    unsigned short* pre_h = bfr;                     // NE u16
    unsigned short* wts   = bfr + NE;                // 8 x 262144 u16
    unsigned short* wq_h = wts;              unsigned short* wq_l = wts + 262144;
    unsigned short* wk_h = wts + 2 * 262144; unsigned short* wk_l = wts + 3 * 262144;
    unsigned short* wv_h = wts + 4 * 262144; unsigned short* wv_l = wts + 5 * 262144;
    unsigned short* wf_h = wts + 6 * 262144; unsigned short* wf_l = wts + 7 * 262144;

    float* tmp = (float*)d_out;
    unsigned short* lnq_h = (unsigned short*)d_out;   // d_out as bf16 scratch
    unsigned short* lnq_l = lnq_h + NE;
    float* part_m   = tmp;                            // later: attn partials
    float* part_s   = part_m + 64 * NTOP * NCH;
    float* part_acc = part_s + 64 * NTOP * NCH;

    // fused preprocessing: ln_split (16384) + wsplit x4 (1024) + padscan (8)
    prep_kernel<<<16384 + 1024 + 8, 256, 0, stream>>>(
        queries, qlnw, qlnb, lnq_h, lnq_l, Wq, Wk, Wv, Wf, wts, pad, denom);

    dim3 gq(4, 128, 3);
    qkv_gemm<<<gq, 256, 0, stream>>>(lnq_h, lnq_l, keys, values,
                                     wq_h, wq_l, wk_h, wk_l, wv_h, wv_l,
                                     bq, bk, bv, qb, kb, kb_h, vb_h);

    // fused: sample_m (4096) + vsum (256)
    sm_vsum_kernel<<<4096 + 256, 256, 0, stream>>>(qb, kb, idx, Mbuf, vb_h, csum);
    // fused: topk (64) + vavg (256)
    topk_vavg_kernel<<<64 + 256, 256, 0, stream>>>(Mbuf, mtop, vb_h, csum, denom, pre_h);
    qprep_kernel<<<64, 256, 0, stream>>>(qb, mtop, pad, qsel, lim_arr);
    dim3 gc(NCH, 64);
    attn_chunk_mfma<<<gc, 256, 0, stream>>>(kb_h, vb_h, qsel, lim_arr,
                                            part_m, part_s, part_acc);
    dim3 gmg(6, 64);
    attn_merge_kernel<<<gmg, 256, 0, stream>>>(part_m, part_s, part_acc, mtop, pre_h);
    dim3 gg(4, 128);
    gemm_mfma<1, 0, 0><<<gg, 256, 0, stream>>>(pre_h, nullptr, nullptr, wf_h, wf_l, bfv, (float*)d_out, nullptr);
    ln_kernel<<<B_ * L, 256, 0, stream>>>((float*)d_out, flnw, flnb, (float*)d_out);
}

// Round 18
// 222.117 us; speedup vs baseline: 1.1473x; 1.0119x over previous
//
#include <hip/hip_runtime.h>
#include <math.h>

#define L 2048
#define DM 512
#define B_ 8
#define H_ 8
#define DH 64
#define SK 24
#define NTOP 24
#define CHUNK 128
#define NCH (L / CHUNK)   // 16
#define VC 32             // vavg chunks
#define VR 64             // rows per vavg chunk
#define ABUF 4096         // u16 per LDS gemm buffer (128 rows x 32 k, swizzled, no pad)

typedef __attribute__((ext_vector_type(8))) short short8;
typedef __attribute__((ext_vector_type(8))) __bf16 bf16x8;
typedef __attribute__((ext_vector_type(4))) float f32x4;

__device__ inline unsigned short f2bf(float x) {
    unsigned u = __float_as_uint(x);
    unsigned r = (u + 0x7FFFu + ((u >> 16) & 1u)) >> 16;
    return (unsigned short)r;
}
__device__ inline float bf2f(unsigned short h) {
    return __uint_as_float(((unsigned)h) << 16);
}

__device__ inline f32x4 MFMA_BF16(short8 a, short8 b, f32x4 c) {
    return __builtin_amdgcn_mfma_f32_16x16x32_bf16(
        __builtin_bit_cast(bf16x8, a), __builtin_bit_cast(bf16x8, b), c, 0, 0, 0);
}

// async global->LDS, 16B/lane; LDS dest must be wave-uniform (+lane*16 implicit)
__device__ __forceinline__ void gload16(const unsigned short* g, unsigned short* l) {
    __builtin_amdgcn_global_load_lds(
        (const __attribute__((address_space(1))) void*)g,
        (__attribute__((address_space(3))) void*)l, 16, 0, 0);
}

// convert 8 f32 (two float4) to bf16 hi (and optionally lo) short8
template<bool WANTL>
__device__ inline void cvt8(const float4& x, const float4& y, short8& h, short8& l) {
    float v0 = x.x, v1 = x.y, v2 = x.z, v3 = x.w;
    float v4 = y.x, v5 = y.y, v6 = y.z, v7 = y.w;
    unsigned short h0 = f2bf(v0), h1 = f2bf(v1), h2 = f2bf(v2), h3 = f2bf(v3);
    unsigned short h4 = f2bf(v4), h5 = f2bf(v5), h6 = f2bf(v6), h7 = f2bf(v7);
    h[0] = (short)h0; h[1] = (short)h1; h[2] = (short)h2; h[3] = (short)h3;
    h[4] = (short)h4; h[5] = (short)h5; h[6] = (short)h6; h[7] = (short)h7;
    if (WANTL) {
        l[0] = (short)f2bf(v0 - bf2f(h0)); l[1] = (short)f2bf(v1 - bf2f(h1));
        l[2] = (short)f2bf(v2 - bf2f(h2)); l[3] = (short)f2bf(v3 - bf2f(h3));
        l[4] = (short)f2bf(v4 - bf2f(h4)); l[5] = (short)f2bf(v5 - bf2f(h5));
        l[6] = (short)f2bf(v6 - bf2f(h6)); l[7] = (short)f2bf(v7 - bf2f(h7));
    }
}

// swizzled LDS address: conflict-free stores, 2-way (free) reads; no padding.
__device__ inline int lds_addr(int row, int kblk) {
    return row * 32 + ((kblk ^ ((row >> 1) & 3)) << 3);
}

// ---------------- reduce helpers ----------------
__device__ inline float waveReduceSum(float v) {
    for (int o = 32; o > 0; o >>= 1) v += __shfl_down(v, o, 64);
    return v;
}

// ---------------- fused preprocessing: ln_split | wsplit x4 | padscan ----------------
__global__ __launch_bounds__(256)
void prep_kernel(const float* __restrict__ queries,
                 const float* __restrict__ qlnw, const float* __restrict__ qlnb,
                 unsigned short* __restrict__ lnq_h, unsigned short* __restrict__ lnq_l,
                 const float* __restrict__ Wq, const float* __restrict__ Wk,
                 const float* __restrict__ Wv, const float* __restrict__ Wf,
                 unsigned short* __restrict__ wts,
                 const float* __restrict__ pad, float* __restrict__ denom) {
    __shared__ float shmem[32 * 33];
    int bid = blockIdx.x;
    int tid = threadIdx.x;
    if (bid < 16384) {
        int row = bid;
        const float* xr = queries + (size_t)row * DM;
        float2 v = *(const float2*)(xr + tid * 2);
        float s = v.x + v.y;
        float sq = v.x * v.x + v.y * v.y;
        float* red = shmem;
        float wsu = waveReduceSum(s);
        float wq = waveReduceSum(sq);
        int wid = tid >> 6, lane = tid & 63;
        if (lane == 0) { red[wid] = wsu; red[4 + wid] = wq; }
        __syncthreads();
        float tot = red[0] + red[1] + red[2] + red[3];
        float totq = red[4] + red[5] + red[6] + red[7];
        float mean = tot * (1.0f / DM);
        float var = totq * (1.0f / DM) - mean * mean;
        float inv = rsqrtf(var + 1e-8f);
        float w0 = qlnw[tid * 2], w1 = qlnw[tid * 2 + 1];
        float b0 = qlnb[tid * 2], b1 = qlnb[tid * 2 + 1];
        float o0 = w0 * (v.x - mean) * inv + b0;
        float o1 = w1 * (v.y - mean) * inv + b1;
        ushort2 hh, ll;
        hh.x = f2bf(o0); ll.x = f2bf(o0 - bf2f(hh.x));
        hh.y = f2bf(o1); ll.y = f2bf(o1 - bf2f(hh.y));
        *(ushort2*)(lnq_h + (size_t)row * DM + tid * 2) = hh;
        *(ushort2*)(lnq_l + (size_t)row * DM + tid * 2) = ll;
    } else if (bid < 16384 + 1024) {
        int idx = bid - 16384;
        int w = idx >> 8;
        int t256 = idx & 255;
        int n0 = (t256 & 15) * 32, k0 = (t256 >> 4) * 32;
        const float* W = (w == 0) ? Wq : (w == 1) ? Wk : (w == 2) ? Wv : Wf;
        unsigned short* th = wts + (size_t)w * 2 * 262144;
        unsigned short* tl = th + 262144;
        float (*ts)[33] = (float(*)[33])shmem;
        int r = tid >> 3, c = (tid & 7) * 4;
        float4 v = *(const float4*)(W + (size_t)(k0 + r) * 512 + n0 + c);
        ts[r][c] = v.x; ts[r][c + 1] = v.y; ts[r][c + 2] = v.z; ts[r][c + 3] = v.w;
        __syncthreads();
        float a0 = ts[c + 0][r], a1 = ts[c + 1][r], a2 = ts[c + 2][r], a3 = ts[c + 3][r];
        ushort4 h, l;
        h.x = f2bf(a0); l.x = f2bf(a0 - bf2f(h.x));
        h.y = f2bf(a1); l.y = f2bf(a1 - bf2f(h.y));
        h.z = f2bf(a2); l.z = f2bf(a2 - bf2f(h.z));
        h.w = f2bf(a3); l.w = f2bf(a3 - bf2f(h.w));
        *(ushort4*)(th + (size_t)(n0 + r) * 512 + k0 + c) = h;
        *(ushort4*)(tl + (size_t)(n0 + r) * 512 + k0 + c) = l;
    } else {
        int b = bid - (16384 + 1024);
        float* tot = shmem;
        const float* p = pad + (size_t)b * L;
        float loc[8];
        float s = 0.f;
#pragma unroll
        for (int u = 0; u < 8; u++) { s += p[tid * 8 + u]; loc[u] = s; }
        tot[tid] = s;
        __syncthreads();
        for (int off = 1; off < 256; off <<= 1) {
            float add = (tid >= off) ? tot[tid - off] : 0.f;
            __syncthreads();
            tot[tid] += add;
            __syncthreads();
        }
        float excl = tot[tid] - s;
#pragma unroll
        for (int u = 0; u < 8; u++) denom[(size_t)b * L + tid * 8 + u] = excl + loc[u];
    }
}

// ---------------- reg-staged GEMM body (K/V branches; ACVT f32->bf16 in-reg) ----
template<int TERMS, int OMODE, int ACVT>
__device__ __forceinline__
void gemm_body(unsigned short* smem,
               const unsigned short* __restrict__ Ah, const unsigned short* __restrict__ Al,
               const float* __restrict__ Af,
               const unsigned short* __restrict__ Bh, const unsigned short* __restrict__ Bl,
               const float* __restrict__ bias, float* __restrict__ C,
               unsigned short* __restrict__ Ch, int orig) {
    unsigned short* sAh = smem;
    unsigned short* sAl = smem + ABUF;                            // TERMS==3 only
    unsigned short* sBh = smem + (TERMS == 3 ? 2 : 1) * ABUF;
    unsigned short* sBl = sBh + ABUF;                             // TERMS>=2 only

    int j = (orig & 7) * 64 + (orig >> 3);
    int n0 = (j & 3) * 128, m0 = (j >> 2) * 128;

    int tid = threadIdx.x;
    int lane = tid & 63, wv = tid >> 6;
    int wr = wv >> 1, wc = wv & 1;
    int lrow = lane & 15, g = lane >> 4;

    int f0 = tid, f1 = tid + 256;
    int row0 = f0 >> 2, k0b = f0 & 3;
    int row1 = f1 >> 2, k1b = f1 & 3;
    int sa0 = lds_addr(row0, k0b), sa1 = lds_addr(row1, k1b);
    int c0 = k0b * 8, c1 = k1b * 8;

    f32x4 acc[4][4];
#pragma unroll
    for (int mf = 0; mf < 4; mf++)
#pragma unroll
        for (int nf = 0; nf < 4; nf++) acc[mf][nf] = (f32x4){0.f, 0.f, 0.f, 0.f};

    short8 rAh0, rAh1, rAl0, rAl1, rBh0, rBh1, rBl0, rBl1;
    float4 fA00, fA01, fA10, fA11;

    auto LOAD = [&](int kt) {
        int k0 = kt * 32;
        if (ACVT) {
            fA00 = *(const float4*)(Af + (size_t)(m0 + row0) * 512 + k0 + c0);
            fA01 = *(const float4*)(Af + (size_t)(m0 + row0) * 512 + k0 + c0 + 4);
            fA10 = *(const float4*)(Af + (size_t)(m0 + row1) * 512 + k0 + c1);
            fA11 = *(const float4*)(Af + (size_t)(m0 + row1) * 512 + k0 + c1 + 4);
        } else {
            rAh0 = *(const short8*)(Ah + (size_t)(m0 + row0) * 512 + k0 + c0);
            rAh1 = *(const short8*)(Ah + (size_t)(m0 + row1) * 512 + k0 + c1);
            if (TERMS == 3) {
                rAl0 = *(const short8*)(Al + (size_t)(m0 + row0) * 512 + k0 + c0);
                rAl1 = *(const short8*)(Al + (size_t)(m0 + row1) * 512 + k0 + c1);
            }
        }
        rBh0 = *(const short8*)(Bh + (size_t)(n0 + row0) * 512 + k0 + c0);
        rBh1 = *(const short8*)(Bh + (size_t)(n0 + row1) * 512 + k0 + c1);
        if (TERMS >= 2) {
            rBl0 = *(const short8*)(Bl + (size_t)(n0 + row0) * 512 + k0 + c0);
            rBl1 = *(const short8*)(Bl + (size_t)(n0 + row1) * 512 + k0 + c1);
        }
    };
    auto STORE = [&]() {
        if (ACVT) {
            cvt8<TERMS == 3>(fA00, fA01, rAh0, rAl0);
            cvt8<TERMS == 3>(fA10, fA11, rAh1, rAl1);
        }
        *(short8*)&sAh[sa0] = rAh0;
        *(short8*)&sAh[sa1] = rAh1;
        if (TERMS == 3) {
            *(short8*)&sAl[sa0] = rAl0;
            *(short8*)&sAl[sa1] = rAl1;
        }
        *(short8*)&sBh[sa0] = rBh0;
        *(short8*)&sBh[sa1] = rBh1;
        if (TERMS >= 2) {
            *(short8*)&sBl[sa0] = rBl0;
            *(short8*)&sBl[sa1] = rBl1;
        }
    };

    int ra = wr * 64 + lrow;
    int rb = wc * 64 + lrow;
    int abase = ra * 32 + ((g ^ ((ra >> 1) & 3)) << 3);
    int bbase = rb * 32 + ((g ^ ((rb >> 1) & 3)) << 3);

    LOAD(0);
    for (int kt = 0; kt < 16; kt++) {
        STORE();
        __syncthreads();
        if (kt < 15) LOAD(kt + 1);
        short8 ah[4], al[4], bh[4], bl[4];
#pragma unroll
        for (int mf = 0; mf < 4; mf++) {
            ah[mf] = *(const short8*)&sAh[abase + mf * 512];
            if (TERMS == 3) al[mf] = *(const short8*)&sAl[abase + mf * 512];
        }
#pragma unroll
        for (int nf = 0; nf < 4; nf++) {
            bh[nf] = *(const short8*)&sBh[bbase + nf * 512];
            if (TERMS >= 2) bl[nf] = *(const short8*)&sBl[bbase + nf * 512];
        }
#pragma unroll
        for (int mf = 0; mf < 4; mf++)
#pragma unroll
            for (int nf = 0; nf < 4; nf++) {
                acc[mf][nf] = MFMA_BF16(ah[mf], bh[nf], acc[mf][nf]);
                if (TERMS >= 2) acc[mf][nf] = MFMA_BF16(ah[mf], bl[nf], acc[mf][nf]);
                if (TERMS == 3) acc[mf][nf] = MFMA_BF16(al[mf], bh[nf], acc[mf][nf]);
            }
        __syncthreads();
    }

    int crow0 = m0 + wr * 64 + (lane >> 4) * 4;
    int ccol0 = n0 + wc * 64 + lrow;
    float bb[4];
#pragma unroll
    for (int nf = 0; nf < 4; nf++) bb[nf] = bias[ccol0 + nf * 16];
#pragma unroll
    for (int mf = 0; mf < 4; mf++)
#pragma unroll
        for (int nf = 0; nf < 4; nf++)
#pragma unroll
            for (int r = 0; r < 4; r++) {
                float val = acc[mf][nf][r] + bb[nf];
                size_t idx = (size_t)(crow0 + mf * 16 + r) * 512 + ccol0 + nf * 16;
                if (OMODE != 2) C[idx] = val;
                if (OMODE != 0) Ch[idx] = f2bf(val);
            }
}

// ---------------- all-gload GEMM body (Q branch / F-GEMM; all operands bf16) ----
// m97 structure: global_load_lds width=16, single buffer, 2 barriers per K-step.
// __syncthreads drains vmcnt (compiler-inserted) -> no manual waitcnt, race-free.
// Pre-swizzled global source column + linear per-wave LDS dest reproduces the
// swizzled layout exactly (pattern HW-verified bit-identical in r16).
template<int TERMS, int OMODE>
__device__ __forceinline__
void gemm_body_gload(unsigned short* smem,
                     const unsigned short* __restrict__ Ah, const unsigned short* __restrict__ Al,
                     const unsigned short* __restrict__ Bh, const unsigned short* __restrict__ Bl,
                     const float* __restrict__ bias, float* __restrict__ C,
                     unsigned short* __restrict__ Ch, int orig) {
    unsigned short* sAh = smem;
    unsigned short* sAl = smem + ABUF;                            // TERMS==3 only
    unsigned short* sBh = smem + (TERMS == 3 ? 2 : 1) * ABUF;
    unsigned short* sBl = sBh + ABUF;                             // TERMS>=2 only

    int j = (orig & 7) * 64 + (orig >> 3);
    int n0 = (j & 3) * 128, m0 = (j >> 2) * 128;

    int tid = threadIdx.x;
    int lane = tid & 63, wv = tid >> 6;
    int wr = wv >> 1, wc = wv & 1;
    int lrow = lane & 15, g = lane >> 4;

    // per-wave slots: rows [wv*16, +16) and [wv*16+64, +16); lane -> (row, kpos)
    int r0 = wv * 16 + (lane >> 2);
    int r1 = r0 + 64;
    int kpos = lane & 3;
    int s0col = (kpos ^ ((r0 >> 1) & 3)) * 8;   // pre-swizzled source column
    int s1col = (kpos ^ ((r1 >> 1) & 3)) * 8;

    f32x4 acc[4][4];
#pragma unroll
    for (int mf = 0; mf < 4; mf++)
#pragma unroll
        for (int nf = 0; nf < 4; nf++) acc[mf][nf] = (f32x4){0.f, 0.f, 0.f, 0.f};

    auto GLOAD_ALL = [&](int kt) {
        int k0 = kt * 32;
        gload16(Ah + (size_t)(m0 + r0) * 512 + k0 + s0col, sAh + wv * 512);
        gload16(Ah + (size_t)(m0 + r1) * 512 + k0 + s1col, sAh + 2048 + wv * 512);
        if (TERMS == 3) {
            gload16(Al + (size_t)(m0 + r0) * 512 + k0 + s0col, sAl + wv * 512);
            gload16(Al + (size_t)(m0 + r1) * 512 + k0 + s1col, sAl + 2048 + wv * 512);
        }
        gload16(Bh + (size_t)(n0 + r0) * 512 + k0 + s0col, sBh + wv * 512);
        gload16(Bh + (size_t)(n0 + r1) * 512 + k0 + s1col, sBh + 2048 + wv * 512);
        if (TERMS >= 2) {
            gload16(Bl + (size_t)(n0 + r0) * 512 + k0 + s0col, sBl + wv * 512);
            gload16(Bl + (size_t)(n0 + r1) * 512 + k0 + s1col, sBl + 2048 + wv * 512);
        }
    };

    int ra = wr * 64 + lrow;
    int rb = wc * 64 + lrow;
    int abase = ra * 32 + ((g ^ ((ra >> 1) & 3)) << 3);
    int bbase = rb * 32 + ((g ^ ((rb >> 1) & 3)) << 3);

    for (int kt = 0; kt < 16; kt++) {
        GLOAD_ALL(kt);
        __syncthreads();                 // drains gloads; LDS image complete
        short8 ah[4], al[4], bh[4], bl[4];
#pragma unroll
        for (int mf = 0; mf < 4; mf++) {
            ah[mf] = *(const short8*)&sAh[abase + mf * 512];
            if (TERMS == 3) al[mf] = *(const short8*)&sAl[abase + mf * 512];
        }
#pragma unroll
        for (int nf = 0; nf < 4; nf++) {
            bh[nf] = *(const short8*)&sBh[bbase + nf * 512];
            if (TERMS >= 2) bl[nf] = *(const short8*)&sBl[bbase + nf * 512];
        }
#pragma unroll
        for (int mf = 0; mf < 4; mf++)
#pragma unroll
            for (int nf = 0; nf < 4; nf++) {
                acc[mf][nf] = MFMA_BF16(ah[mf], bh[nf], acc[mf][nf]);
                if (TERMS >= 2) acc[mf][nf] = MFMA_BF16(ah[mf], bl[nf], acc[mf][nf]);
                if (TERMS == 3) acc[mf][nf] = MFMA_BF16(al[mf], bh[nf], acc[mf][nf]);
            }
        __syncthreads();                 // reads done before next overwrite
    }

    int crow0 = m0 + wr * 64 + (lane >> 4) * 4;
    int ccol0 = n0 + wc * 64 + lrow;
    float bb[4];
#pragma unroll
    for (int nf = 0; nf < 4; nf++) bb[nf] = bias[ccol0 + nf * 16];
#pragma unroll
    for (int mf = 0; mf < 4; mf++)
#pragma unroll
        for (int nf = 0; nf < 4; nf++)
#pragma unroll
            for (int r = 0; r < 4; r++) {
                float val = acc[mf][nf][r] + bb[nf];
                size_t idx = (size_t)(crow0 + mf * 16 + r) * 512 + ccol0 + nf * 16;
                if (OMODE != 2) C[idx] = val;
                if (OMODE != 0) Ch[idx] = f2bf(val);
            }
}

// fused Q/K/V GEMM (blockIdx.z selects sub-GEMM); 32KB LDS
__global__ __launch_bounds__(256, 2)
void qkv_gemm(const unsigned short* __restrict__ lnq_h, const unsigned short* __restrict__ lnq_l,
              const float* __restrict__ keys, const float* __restrict__ values,
              const unsigned short* __restrict__ wq_h, const unsigned short* __restrict__ wq_l,
              const unsigned short* __restrict__ wk_h, const unsigned short* __restrict__ wk_l,
              const unsigned short* __restrict__ wv_h, const unsigned short* __restrict__ wv_l,
              const float* __restrict__ bq, const float* __restrict__ bk, const float* __restrict__ bv,
              float* __restrict__ qb, float* __restrict__ kb,
              unsigned short* __restrict__ kb_h, unsigned short* __restrict__ vb_h) {
    __shared__ __align__(16) unsigned short smem[4 * ABUF];  // 32KB
    int orig = blockIdx.x + 4 * blockIdx.y;
    if (blockIdx.z == 0)
        gemm_body_gload<3, 0>(smem, lnq_h, lnq_l, wq_h, wq_l, bq, qb, nullptr, orig);
    else if (blockIdx.z == 1)
        gemm_body<3, 1, 1>(smem, nullptr, nullptr, keys, wk_h, wk_l, bk, kb, kb_h, orig);
    else
        gemm_body<1, 2, 1>(smem, nullptr, nullptr, values, wv_h, wv_l, bv, nullptr, vb_h, orig);
}

// standalone F-GEMM: all-gload, 1-term -> 16KB LDS
__global__ __launch_bounds__(256, 2)
void fgemm_kernel(const unsigned short* __restrict__ Ah,
                  const unsigned short* __restrict__ Bh,
                  const float* __restrict__ bias, float* __restrict__ C) {
    __shared__ __align__(16) unsigned short smem[2 * ABUF];
    int orig = blockIdx.x + 4 * blockIdx.y;
    gemm_body_gload<1, 0>(smem, Ah, nullptr, Bh, nullptr, bias, C, nullptr, orig);
}

// ---------------- fused: sample_m | vsum ----------------
__global__ __launch_bounds__(256)
void sm_vsum_kernel(const float* __restrict__ q, const float* __restrict__ k,
                    const int* __restrict__ idx, float* __restrict__ M,
                    const unsigned short* __restrict__ vh, float* __restrict__ csum) {
    int bid = blockIdx.x;
    if (bid < 4096) {
        int b = bid & 7;
        int ig = bid >> 3;
        int wv = threadIdx.x >> 6, lane = threadIdx.x & 63;
        int i = ig * 4 + wv;
        const float* qrow = q + ((size_t)b * L + i) * DM + lane * 8;
        float4 q0 = *(const float4*)qrow;
        float4 q1 = *(const float4*)(qrow + 4);
        int myidx = 0;
        if (lane < SK) myidx = idx[i * SK + lane];
        float sj[SK];
#pragma unroll
        for (int j = 0; j < SK; j++) {
            int row = __shfl(myidx, j, 64);
            const float* kp = k + ((size_t)b * L + row) * DM + lane * 8;
            float4 k0 = *(const float4*)kp;
            float4 k1 = *(const float4*)(kp + 4);
            sj[j] = q0.x * k0.x + q0.y * k0.y + q0.z * k0.z + q0.w * k0.w
                  + q1.x * k1.x + q1.y * k1.y + q1.z * k1.z + q1.w * k1.w;
        }
        float mx = -1e30f, sm = 0.f;
#pragma unroll
        for (int j = 0; j < SK; j++) {
            float s = sj[j];
            s += __shfl_xor(s, 1, 64);
            s += __shfl_xor(s, 2, 64);
            s += __shfl_xor(s, 4, 64);
            mx = fmaxf(mx, s);
            sm += s;
        }
        if ((lane & 7) == 0) {
            int h = lane >> 3;
            M[((size_t)b * H_ + h) * L + i] = mx - sm * (1.0f / L);
        }
    } else {
        int t = bid - 4096;
        int c = t & (VC - 1), b = t >> 5;
        int d2 = threadIdx.x;
        size_t base = ((size_t)b * L + c * VR) * DM + d2 * 2;
        float a0 = 0.f, a1 = 0.f;
        for (int tt = 0; tt < VR; tt++) {
            unsigned v = *(const unsigned*)(vh + base + (size_t)tt * DM);
            a0 += bf2f((unsigned short)(v & 0xffff));
            a1 += bf2f((unsigned short)(v >> 16));
        }
        float2 st = {a0, a1};
        *(float2*)(csum + ((size_t)b * VC + c) * DM + d2 * 2) = st;
    }
}

// ---------------- fused: topk | vavg ----------------
__global__ __launch_bounds__(256)
void topk_vavg_kernel(const float* __restrict__ M, int* __restrict__ mtop,
                      const unsigned short* __restrict__ vh, const float* __restrict__ csum,
                      const float* __restrict__ denom, unsigned short* __restrict__ out_h) {
    int bid = blockIdx.x;
    if (bid < 64) {
        if (threadIdx.x >= 64) return;
        int bh = bid;
        int lane = threadIdx.x;
        const float* Mr = M + (size_t)bh * L;
        float m[32];
#pragma unroll
        for (int r = 0; r < 32; r++) m[r] = Mr[r * 64 + lane];
        for (int it = 0; it < NTOP; it++) {
            float bv = -1e30f; int br = 0;
#pragma unroll
            for (int r = 0; r < 32; r++) {
                bool better = m[r] > bv;   // strict > keeps lowest r on ties
                br = better ? r : br;
                bv = better ? m[r] : bv;
            }
            int bt = (br << 6) | lane;
#pragma unroll
            for (int o = 1; o < 64; o <<= 1) {
                float ov = __shfl_xor(bv, o, 64);
                int ot = __shfl_xor(bt, o, 64);
                bool take = (ov > bv) || (ov == bv && ot < bt);
                bv = take ? ov : bv;
                bt = take ? ot : bt;
            }
            if (lane == 0) mtop[bh * NTOP + it] = bt;
            int rwin = bt >> 6;
            bool mine = (bt & 63) == lane;
#pragma unroll
            for (int r = 0; r < 32; r++)
                if (mine && (r == rwin)) m[r] = -1e30f;
        }
    } else {
        int t = bid - 64;
        int c = t & (VC - 1), b = t >> 5;
        int d2 = threadIdx.x;
        float a0 = 0.f, a1 = 0.f;
        for (int cc = 0; cc < c; cc++) {
            float2 tt = *(const float2*)(csum + ((size_t)b * VC + cc) * DM + d2 * 2);
            a0 += tt.x; a1 += tt.y;
        }
        size_t base = ((size_t)b * L + c * VR) * DM + d2 * 2;
        for (int tt = 0; tt < VR; tt++) {
            unsigned v = *(const unsigned*)(vh + base + (size_t)tt * DM);
            a0 += bf2f((unsigned short)(v & 0xffff));
            a1 += bf2f((unsigned short)(v >> 16));
            float dn = denom[(size_t)b * L + c * VR + tt] + 1e-12f;
            unsigned o = (unsigned)f2bf(a0 / dn) | ((unsigned)f2bf(a1 / dn) << 16);
            *(unsigned*)(out_h + base + (size_t)tt * DM) = o;
        }
    }
}

// ---------------- Q gather + pre-scale + lim prep (parallel) ----------------
__global__ __launch_bounds__(256)
void qprep_kernel(const float* __restrict__ qb, const int* __restrict__ mtop,
                  const float* __restrict__ pad, unsigned short* __restrict__ qsel,
                  int* __restrict__ lim_arr) {
    int bh = blockIdx.x; int b = bh >> 3, h = bh & 7;
    int tid = threadIdx.x;
#pragma unroll
    for (int l = 0; l < 2; l++) {
        int f = tid + l * 256;
        int u = f >> 4, seg = (f & 15) * 4;
        ushort4 o;
        if (u < NTOP) {
            int iq = mtop[bh * NTOP + u];
            bool ok = pad[(size_t)b * L + iq] != 0.f;
            float sc = ok ? 0.044194173824159216f : 0.f;
            float4 qv = *(const float4*)(qb + ((size_t)b * L + iq) * DM + h * DH + seg);
            o.x = f2bf(qv.x * sc); o.y = f2bf(qv.y * sc);
            o.z = f2bf(qv.z * sc); o.w = f2bf(qv.w * sc);
            if (seg == 0) lim_arr[bh * 32 + u] = ok ? iq : (L - 1);
        } else {
            o.x = o.y = o.z = o.w = 0;
            if (seg == 0) lim_arr[bh * 32 + u] = -1;
        }
        *(ushort4*)(qsel + ((size_t)bh * 32 + u) * 64 + seg) = o;
    }
}

// ---------------- MFMA split-chunk sparse attention ----------------
__global__ __launch_bounds__(256)
void attn_chunk_mfma(const unsigned short* __restrict__ kbh,
                     const unsigned short* __restrict__ vbh,
                     const unsigned short* __restrict__ qsel,
                     const int* __restrict__ lim_arr,
                     float* __restrict__ part_m, float* __restrict__ part_s,
                     float* __restrict__ part_acc) {
    int c = blockIdx.x, bh = blockIdx.y;
    int b = bh >> 3, h = bh & 7;
    int j0 = c * CHUNK;
    __shared__ __align__(16) unsigned short KV[128 * 64];
    __shared__ __align__(16) unsigned short Ps[32 * 128];
    __shared__ __align__(16) unsigned short Qs[32 * 64];
    __shared__ float redm[4][32];
    __shared__ float reds[4][32];
    __shared__ int lims[32];

    int tid = threadIdx.x;
    int wv = tid >> 6, lane = tid & 63;
    int l15 = lane & 15, g = lane >> 4;

    const unsigned short* kpanel = kbh + ((size_t)b * L + j0) * DM + h * DH;
    short8 kreg[4];
#pragma unroll
    for (int l = 0; l < 4; l++) {
        int f = tid + l * 256;
        int jr = f >> 3, blk = f & 7;
        kreg[l] = *(const short8*)(kpanel + (size_t)jr * DM + blk * 8);
    }
    {
        int u = tid >> 3, blk = tid & 7;
        short8 qreg = *(const short8*)(qsel + ((size_t)bh * 32 + u) * 64 + blk * 8);
        *(short8*)&Qs[u * 64 + (((blk ^ (u & 7))) << 3)] = qreg;
    }
#pragma unroll
    for (int l = 0; l < 4; l++) {
        int f = tid + l * 256;
        int jr = f >> 3, blk = f & 7;
        *(short8*)&KV[jr * 64 + ((blk ^ (jr & 7)) << 3)] = kreg[l];
    }
    if (tid < 32) lims[tid] = lim_arr[bh * 32 + tid];
    __syncthreads();

    f32x4 sf[2][2];
#pragma unroll
    for (int mf = 0; mf < 2; mf++)
#pragma unroll
        for (int nf = 0; nf < 2; nf++) sf[mf][nf] = (f32x4){0.f, 0.f, 0.f, 0.f};
#pragma unroll
    for (int ks = 0; ks < 2; ks++) {
        short8 aq[2], bk[2];
#pragma unroll
        for (int mf = 0; mf < 2; mf++) {
            int u = mf * 16 + l15;
            int blk = (ks * 4 + g) ^ (u & 7);
            aq[mf] = *(const short8*)&Qs[u * 64 + (blk << 3)];
        }
#pragma unroll
        for (int nf = 0; nf < 2; nf++) {
            int jr = wv * 32 + nf * 16 + l15;
            int blk = (ks * 4 + g) ^ (jr & 7);
            bk[nf] = *(const short8*)&KV[jr * 64 + (blk << 3)];
        }
#pragma unroll
        for (int mf = 0; mf < 2; mf++)
#pragma unroll
            for (int nf = 0; nf < 2; nf++)
                sf[mf][nf] = MFMA_BF16(aq[mf], bk[nf], sf[mf][nf]);
    }

    const unsigned short* vpanel = vbh + ((size_t)b * L + j0) * DM + h * DH;
    short8 vreg[4];
#pragma unroll
    for (int l = 0; l < 4; l++) {
        int f = tid + l * 256;
        int jr = f >> 3, blk = f & 7;
        vreg[l] = *(const short8*)(vpanel + (size_t)jr * DM + blk * 8);
    }

    float sv[2][2][4];
    float mx[2][4];
#pragma unroll
    for (int mf = 0; mf < 2; mf++)
#pragma unroll
        for (int r = 0; r < 4; r++) {
            int u = mf * 16 + g * 4 + r;
            int limv = lims[u];
            float m = -1e30f;
#pragma unroll
            for (int nf = 0; nf < 2; nf++) {
                int jg = j0 + wv * 32 + nf * 16 + l15;
                float s = (jg <= limv) ? sf[mf][nf][r] : -1e30f;
                sv[mf][nf][r] = s;
                m = fmaxf(m, s);
            }
            m = fmaxf(m, __shfl_xor(m, 1, 64));
            m = fmaxf(m, __shfl_xor(m, 2, 64));
            m = fmaxf(m, __shfl_xor(m, 4, 64));
            m = fmaxf(m, __shfl_xor(m, 8, 64));
            mx[mf][r] = m;
        }
    if (l15 == 0) {
#pragma unroll
        for (int mf = 0; mf < 2; mf++)
#pragma unroll
            for (int r = 0; r < 4; r++)
                redm[wv][mf * 16 + g * 4 + r] = mx[mf][r];
    }
    __syncthreads();

    float lmax[2][4], smv[2][4];
#pragma unroll
    for (int mf = 0; mf < 2; mf++)
#pragma unroll
        for (int r = 0; r < 4; r++) {
            int u = mf * 16 + g * 4 + r;
            float m = fmaxf(fmaxf(redm[0][u], redm[1][u]),
                            fmaxf(redm[2][u], redm[3][u]));
            lmax[mf][r] = m;
            bool any = m > -1e29f;
            float sm = 0.f;
#pragma unroll
            for (int nf = 0; nf < 2; nf++) {
                float e = any ? __expf(sv[mf][nf][r] - m) : 0.f;
                sm += e;
                int jr = wv * 32 + nf * 16 + l15;
                Ps[u * 128 + (((jr >> 3) ^ (u & 7)) << 3) + (jr & 7)] = f2bf(e);
            }
            sm += __shfl_xor(sm, 1, 64);
            sm += __shfl_xor(sm, 2, 64);
            sm += __shfl_xor(sm, 4, 64);
            sm += __shfl_xor(sm, 8, 64);
            smv[mf][r] = sm;
        }
    if (l15 == 0) {
#pragma unroll
        for (int mf = 0; mf < 2; mf++)
#pragma unroll
            for (int r = 0; r < 4; r++)
                reds[wv][mf * 16 + g * 4 + r] = smv[mf][r];
    }
#pragma unroll
    for (int l = 0; l < 4; l++) {
        int f = tid + l * 256;
        int jr = f >> 3, blk = f & 7;
        short8 w = vreg[l];
        if ((jr >> 3) & 1) w = __builtin_shufflevector(w, w, 4, 5, 6, 7, 0, 1, 2, 3);
        *(short8*)&KV[jr * 64 + ((blk ^ (jr & 7)) << 3)] = w;
    }
    __syncthreads();

    if (wv == 0 && l15 == 0) {
#pragma unroll
        for (int mf = 0; mf < 2; mf++)
#pragma unroll
            for (int r = 0; r < 4; r++) {
                int u = mf * 16 + g * 4 + r;
                if (u < NTOP) {
                    float ss = reds[0][u] + reds[1][u] + reds[2][u] + reds[3][u];
                    part_m[(bh * NTOP + u) * NCH + c] = lmax[mf][r];
                    part_s[(bh * NTOP + u) * NCH + c] = ss;
                }
            }
    }

    f32x4 of[2];
    of[0] = (f32x4){0.f, 0.f, 0.f, 0.f};
    of[1] = (f32x4){0.f, 0.f, 0.f, 0.f};
    int d = wv * 16 + l15;
#pragma unroll
    for (int ks = 0; ks < 4; ks++) {
        unsigned short va[8];
#pragma unroll
        for (int i = 0; i < 8; i++) {
            int jr = ks * 32 + g * 8 + i;
            int addr = jr * 64 + (((d >> 3) ^ (jr & 7)) << 3)
                     + ((d & 7) ^ (((jr >> 3) & 1) << 2));
            va[i] = KV[addr];
        }
        short8 av;
#pragma unroll
        for (int i = 0; i < 8; i++) av[i] = (short)va[i];
        short8 bp[2];
#pragma unroll
        for (int nf = 0; nf < 2; nf++) {
            int u = nf * 16 + l15;
            int blk = (ks * 4 + g) ^ (u & 7);
            bp[nf] = *(const short8*)&Ps[u * 128 + (blk << 3)];
        }
#pragma unroll
        for (int nf = 0; nf < 2; nf++)
            of[nf] = MFMA_BF16(av, bp[nf], of[nf]);
    }
#pragma unroll
    for (int nf = 0; nf < 2; nf++) {
        int u = nf * 16 + l15;
        if (u < NTOP) {
#pragma unroll
            for (int r = 0; r < 4; r++)
                part_acc[((size_t)(bh * NTOP + u) * NCH + c) * 64 + wv * 16 + g * 4 + r] =
                    of[nf][r];
        }
    }
}

// merge 16 chunk partials per (bh,u); scatter bf16 into pre_h
__global__ __launch_bounds__(256)
void attn_merge_kernel(const float* __restrict__ part_m, const float* __restrict__ part_s,
                       const float* __restrict__ part_acc, const int* __restrict__ mtop,
                       unsigned short* __restrict__ pre_h) {
    int ug = blockIdx.x;
    int bh = blockIdx.y;
    int b = bh >> 3, h = bh & 7;
    int tid = threadIdx.x;
    int u = ug * 4 + (tid >> 6);
    int d = tid & 63;
    int base = (bh * NTOP + u) * NCH;
    float m = -1e30f;
#pragma unroll
    for (int c = 0; c < NCH; c++) m = fmaxf(m, part_m[base + c]);
    float s = 0.f, o = 0.f;
#pragma unroll
    for (int c = 0; c < NCH; c++) {
        float w = __expf(part_m[base + c] - m);
        s += part_s[base + c] * w;
        o = fmaf(part_acc[(size_t)(base + c) * 64 + d], w, o);
    }
    o /= s;
    int iq = mtop[bh * NTOP + u];
    pre_h[((size_t)b * L + iq) * DM + h * DH + d] = f2bf(o);
}

// ---------------- final LayerNorm (row-wise, 512 cols) ----------------
__global__ __launch_bounds__(256)
void ln_kernel(const float* __restrict__ x, const float* __restrict__ w,
               const float* __restrict__ bvec, float* __restrict__ out) {
    int row = blockIdx.x;
    const float* xr = x + (size_t)row * DM;
    float* orow = out + (size_t)row * DM;
    int tid = threadIdx.x;
    float2 v = *(const float2*)(xr + tid * 2);
    float s = v.x + v.y;
    float sq = v.x * v.x + v.y * v.y;
    __shared__ float red[8];
    float ws = waveReduceSum(s);
    float wq = waveReduceSum(sq);
    int wid = tid >> 6, lane = tid & 63;
    if (lane == 0) { red[wid] = ws; red[4 + wid] = wq; }
    __syncthreads();
    float tot = red[0] + red[1] + red[2] + red[3];
    float totq = red[4] + red[5] + red[6] + red[7];
    float mean = tot * (1.0f / DM);
    float var = totq * (1.0f / DM) - mean * mean;
    float inv = rsqrtf(var + 1e-8f);
    float w0 = w[tid * 2], w1 = w[tid * 2 + 1];
    float b0 = bvec[tid * 2], b1 = bvec[tid * 2 + 1];
    float2 o;
    o.x = w0 * (v.x - mean) * inv + b0;
    o.y = w1 * (v.y - mean) * inv + b1;
    *(float2*)(orow + tid * 2) = o;
}

extern "C" void kernel_launch(void* const* d_in, const int* in_sizes, int n_in,
                              void* d_out, int out_size, void* d_ws, size_t ws_size,
                              hipStream_t stream) {
    const float* queries = (const float*)d_in[0];
    const float* keys    = (const float*)d_in[1];
    const float* values  = (const float*)d_in[2];
    const float* pad     = (const float*)d_in[3];
    const float* Wq = (const float*)d_in[4];  const float* bq = (const float*)d_in[5];
    const float* Wk = (const float*)d_in[6];  const float* bk = (const float*)d_in[7];
    const float* Wv = (const float*)d_in[8];  const float* bv = (const float*)d_in[9];
    const float* Wf = (const float*)d_in[10]; const float* bfv = (const float*)d_in[11];
    const float* qlnw = (const float*)d_in[12]; const float* qlnb = (const float*)d_in[13];
    const float* flnw = (const float*)d_in[14]; const float* flnb = (const float*)d_in[15];
    const int* idx = (const int*)d_in[16];

    float* ws = (float*)d_ws;
    const size_t NE = (size_t)B_ * L * DM;   // 8388608
    float* qb    = ws;
    float* kb    = ws + NE;
    unsigned short* vb_h = (unsigned short*)(ws + 2 * NE);   // NE u16
    unsigned short* kb_h = vb_h + NE;                        // NE u16
    unsigned short* qsel = (unsigned short*)(ws + 3 * NE);   // 64*32*64 u16
    int* lim_arr = (int*)(qsel + 64 * 32 * 64);              // 2048 ints
    float* Mbuf  = ws + 4 * NE;                      // 64*2048
    float* denom = Mbuf + (size_t)B_ * H_ * L;       // 8*2048
    float* csum  = denom + (size_t)B_ * L;           // 8*32*512
    int*   mtop  = (int*)(csum + (size_t)B_ * VC * DM);
    unsigned short* bfr = (unsigned short*)(mtop + 2048);
    unsigned short* pre_h = bfr;                     // NE u16
    unsigned short* wts   = bfr + NE;                // 8 x 262144 u16
    unsigned short* wq_h = wts;              unsigned short* wq_l = wts + 262144;
    unsigned short* wk_h = wts + 2 * 262144; unsigned short* wk_l = wts + 3 * 262144;
    unsigned short* wv_h = wts + 4 * 262144; unsigned short* wv_l = wts + 5 * 262144;
    unsigned short* wf_h = wts + 6 * 262144; unsigned short* wf_l = wts + 7 * 262144;

    float* tmp = (float*)d_out;
    unsigned short* lnq_h = (unsigned short*)d_out;   // d_out as bf16 scratch
    unsigned short* lnq_l = lnq_h + NE;
    float* part_m   = tmp;                            // later: attn partials
    float* part_s   = part_m + 64 * NTOP * NCH;
    float* part_acc = part_s + 64 * NTOP * NCH;

    // fused preprocessing: ln_split (16384) + wsplit x4 (1024) + padscan (8)
    prep_kernel<<<16384 + 1024 + 8, 256, 0, stream>>>(
        queries, qlnw, qlnb, lnq_h, lnq_l, Wq, Wk, Wv, Wf, wts, pad, denom);

    dim3 gq(4, 128, 3);
    qkv_gemm<<<gq, 256, 0, stream>>>(lnq_h, lnq_l, keys, values,
                                     wq_h, wq_l, wk_h, wk_l, wv_h, wv_l,
                                     bq, bk, bv, qb, kb, kb_h, vb_h);

    sm_vsum_kernel<<<4096 + 256, 256, 0, stream>>>(qb, kb, idx, Mbuf, vb_h, csum);
    topk_vavg_kernel<<<64 + 256, 256, 0, stream>>>(Mbuf, mtop, vb_h, csum, denom, pre_h);
    qprep_kernel<<<64, 256, 0, stream>>>(qb, mtop, pad, qsel, lim_arr);
    dim3 gc(NCH, 64);
    attn_chunk_mfma<<<gc, 256, 0, stream>>>(kb_h, vb_h, qsel, lim_arr,
                                            part_m, part_s, part_acc);
    dim3 gmg(6, 64);
    attn_merge_kernel<<<gmg, 256, 0, stream>>>(part_m, part_s, part_acc, mtop, pre_h);
    dim3 gg(4, 128);
    fgemm_kernel<<<gg, 256, 0, stream>>>(pre_h, wf_h, bfv, (float*)d_out);
    ln_kernel<<<B_ * L, 256, 0, stream>>>((float*)d_out, flnw, flnb, (float*)d_out);
}

// Round 19
// 221.626 us; speedup vs baseline: 1.1498x; 1.0022x over previous
//
#include <hip/hip_runtime.h>
#include <math.h>

#define L 2048
#define DM 512
#define B_ 8
#define H_ 8
#define DH 64
#define SK 24
#define NTOP 24
#define CHUNK 128
#define NCH (L / CHUNK)   // 16
#define VC 32             // vavg chunks
#define VR 64             // rows per vavg chunk
#define ABUF 4096         // u16 per LDS gemm buffer (128 rows x 32 k, swizzled, no pad)

typedef __attribute__((ext_vector_type(8))) short short8;
typedef __attribute__((ext_vector_type(8))) __bf16 bf16x8;
typedef __attribute__((ext_vector_type(4))) float f32x4;

__device__ inline unsigned short f2bf(float x) {
    unsigned u = __float_as_uint(x);
    unsigned r = (u + 0x7FFFu + ((u >> 16) & 1u)) >> 16;
    return (unsigned short)r;
}
__device__ inline float bf2f(unsigned short h) {
    return __uint_as_float(((unsigned)h) << 16);
}

__device__ inline f32x4 MFMA_BF16(short8 a, short8 b, f32x4 c) {
    return __builtin_amdgcn_mfma_f32_16x16x32_bf16(
        __builtin_bit_cast(bf16x8, a), __builtin_bit_cast(bf16x8, b), c, 0, 0, 0);
}

// async global->LDS, 16B/lane; LDS dest must be wave-uniform (+lane*16 implicit)
__device__ __forceinline__ void gload16(const unsigned short* g, unsigned short* l) {
    __builtin_amdgcn_global_load_lds(
        (const __attribute__((address_space(1))) void*)g,
        (__attribute__((address_space(3))) void*)l, 16, 0, 0);
}

// convert 8 f32 (two float4) to bf16 hi (and optionally lo) short8
template<bool WANTL>
__device__ inline void cvt8(const float4& x, const float4& y, short8& h, short8& l) {
    float v0 = x.x, v1 = x.y, v2 = x.z, v3 = x.w;
    float v4 = y.x, v5 = y.y, v6 = y.z, v7 = y.w;
    unsigned short h0 = f2bf(v0), h1 = f2bf(v1), h2 = f2bf(v2), h3 = f2bf(v3);
    unsigned short h4 = f2bf(v4), h5 = f2bf(v5), h6 = f2bf(v6), h7 = f2bf(v7);
    h[0] = (short)h0; h[1] = (short)h1; h[2] = (short)h2; h[3] = (short)h3;
    h[4] = (short)h4; h[5] = (short)h5; h[6] = (short)h6; h[7] = (short)h7;
    if (WANTL) {
        l[0] = (short)f2bf(v0 - bf2f(h0)); l[1] = (short)f2bf(v1 - bf2f(h1));
        l[2] = (short)f2bf(v2 - bf2f(h2)); l[3] = (short)f2bf(v3 - bf2f(h3));
        l[4] = (short)f2bf(v4 - bf2f(h4)); l[5] = (short)f2bf(v5 - bf2f(h5));
        l[6] = (short)f2bf(v6 - bf2f(h6)); l[7] = (short)f2bf(v7 - bf2f(h7));
    }
}

// swizzled LDS address: conflict-free stores, 2-way (free) reads; no padding.
__device__ inline int lds_addr(int row, int kblk) {
    return row * 32 + ((kblk ^ ((row >> 1) & 3)) << 3);
}

// ---------------- reduce helpers ----------------
__device__ inline float waveReduceSum(float v) {
    for (int o = 32; o > 0; o >>= 1) v += __shfl_down(v, o, 64);
    return v;
}

// ---------------- fused preprocessing: ln_split | wsplit x4 | padscan ----------------
__global__ __launch_bounds__(256)
void prep_kernel(const float* __restrict__ queries,
                 const float* __restrict__ qlnw, const float* __restrict__ qlnb,
                 unsigned short* __restrict__ lnq_h, unsigned short* __restrict__ lnq_l,
                 const float* __restrict__ Wq, const float* __restrict__ Wk,
                 const float* __restrict__ Wv, const float* __restrict__ Wf,
                 unsigned short* __restrict__ wts,
                 const float* __restrict__ pad, float* __restrict__ denom) {
    __shared__ float shmem[32 * 33];
    int bid = blockIdx.x;
    int tid = threadIdx.x;
    if (bid < 16384) {
        int row = bid;
        const float* xr = queries + (size_t)row * DM;
        float2 v = *(const float2*)(xr + tid * 2);
        float s = v.x + v.y;
        float sq = v.x * v.x + v.y * v.y;
        float* red = shmem;
        float wsu = waveReduceSum(s);
        float wq = waveReduceSum(sq);
        int wid = tid >> 6, lane = tid & 63;
        if (lane == 0) { red[wid] = wsu; red[4 + wid] = wq; }
        __syncthreads();
        float tot = red[0] + red[1] + red[2] + red[3];
        float totq = red[4] + red[5] + red[6] + red[7];
        float mean = tot * (1.0f / DM);
        float var = totq * (1.0f / DM) - mean * mean;
        float inv = rsqrtf(var + 1e-8f);
        float w0 = qlnw[tid * 2], w1 = qlnw[tid * 2 + 1];
        float b0 = qlnb[tid * 2], b1 = qlnb[tid * 2 + 1];
        float o0 = w0 * (v.x - mean) * inv + b0;
        float o1 = w1 * (v.y - mean) * inv + b1;
        ushort2 hh, ll;
        hh.x = f2bf(o0); ll.x = f2bf(o0 - bf2f(hh.x));
        hh.y = f2bf(o1); ll.y = f2bf(o1 - bf2f(hh.y));
        *(ushort2*)(lnq_h + (size_t)row * DM + tid * 2) = hh;
        *(ushort2*)(lnq_l + (size_t)row * DM + tid * 2) = ll;
    } else if (bid < 16384 + 1024) {
        int idx = bid - 16384;
        int w = idx >> 8;
        int t256 = idx & 255;
        int n0 = (t256 & 15) * 32, k0 = (t256 >> 4) * 32;
        const float* W = (w == 0) ? Wq : (w == 1) ? Wk : (w == 2) ? Wv : Wf;
        unsigned short* th = wts + (size_t)w * 2 * 262144;
        unsigned short* tl = th + 262144;
        float (*ts)[33] = (float(*)[33])shmem;
        int r = tid >> 3, c = (tid & 7) * 4;
        float4 v = *(const float4*)(W + (size_t)(k0 + r) * 512 + n0 + c);
        ts[r][c] = v.x; ts[r][c + 1] = v.y; ts[r][c + 2] = v.z; ts[r][c + 3] = v.w;
        __syncthreads();
        float a0 = ts[c + 0][r], a1 = ts[c + 1][r], a2 = ts[c + 2][r], a3 = ts[c + 3][r];
        ushort4 h, l;
        h.x = f2bf(a0); l.x = f2bf(a0 - bf2f(h.x));
        h.y = f2bf(a1); l.y = f2bf(a1 - bf2f(h.y));
        h.z = f2bf(a2); l.z = f2bf(a2 - bf2f(h.z));
        h.w = f2bf(a3); l.w = f2bf(a3 - bf2f(h.w));
        *(ushort4*)(th + (size_t)(n0 + r) * 512 + k0 + c) = h;
        *(ushort4*)(tl + (size_t)(n0 + r) * 512 + k0 + c) = l;
    } else {
        int b = bid - (16384 + 1024);
        float* tot = shmem;
        const float* p = pad + (size_t)b * L;
        float loc[8];
        float s = 0.f;
#pragma unroll
        for (int u = 0; u < 8; u++) { s += p[tid * 8 + u]; loc[u] = s; }
        tot[tid] = s;
        __syncthreads();
        for (int off = 1; off < 256; off <<= 1) {
            float add = (tid >= off) ? tot[tid - off] : 0.f;
            __syncthreads();
            tot[tid] += add;
            __syncthreads();
        }
        float excl = tot[tid] - s;
#pragma unroll
        for (int u = 0; u < 8; u++) denom[(size_t)b * L + tid * 8 + u] = excl + loc[u];
    }
}

// ---------------- reg-staged GEMM body (K/V branches; ACVT f32->bf16 in-reg) ----
template<int TERMS, int OMODE, int ACVT>
__device__ __forceinline__
void gemm_body(unsigned short* smem,
               const unsigned short* __restrict__ Ah, const unsigned short* __restrict__ Al,
               const float* __restrict__ Af,
               const unsigned short* __restrict__ Bh, const unsigned short* __restrict__ Bl,
               const float* __restrict__ bias, float* __restrict__ C,
               unsigned short* __restrict__ Ch, int orig) {
    unsigned short* sAh = smem;
    unsigned short* sAl = smem + ABUF;                            // TERMS==3 only
    unsigned short* sBh = smem + (TERMS == 3 ? 2 : 1) * ABUF;
    unsigned short* sBl = sBh + ABUF;                             // TERMS>=2 only

    int j = (orig & 7) * 64 + (orig >> 3);
    int n0 = (j & 3) * 128, m0 = (j >> 2) * 128;

    int tid = threadIdx.x;
    int lane = tid & 63, wv = tid >> 6;
    int wr = wv >> 1, wc = wv & 1;
    int lrow = lane & 15, g = lane >> 4;

    int f0 = tid, f1 = tid + 256;
    int row0 = f0 >> 2, k0b = f0 & 3;
    int row1 = f1 >> 2, k1b = f1 & 3;
    int sa0 = lds_addr(row0, k0b), sa1 = lds_addr(row1, k1b);
    int c0 = k0b * 8, c1 = k1b * 8;

    f32x4 acc[4][4];
#pragma unroll
    for (int mf = 0; mf < 4; mf++)
#pragma unroll
        for (int nf = 0; nf < 4; nf++) acc[mf][nf] = (f32x4){0.f, 0.f, 0.f, 0.f};

    short8 rAh0, rAh1, rAl0, rAl1, rBh0, rBh1, rBl0, rBl1;
    float4 fA00, fA01, fA10, fA11;

    auto LOAD = [&](int kt) {
        int k0 = kt * 32;
        if (ACVT) {
            fA00 = *(const float4*)(Af + (size_t)(m0 + row0) * 512 + k0 + c0);
            fA01 = *(const float4*)(Af + (size_t)(m0 + row0) * 512 + k0 + c0 + 4);
            fA10 = *(const float4*)(Af + (size_t)(m0 + row1) * 512 + k0 + c1);
            fA11 = *(const float4*)(Af + (size_t)(m0 + row1) * 512 + k0 + c1 + 4);
        } else {
            rAh0 = *(const short8*)(Ah + (size_t)(m0 + row0) * 512 + k0 + c0);
            rAh1 = *(const short8*)(Ah + (size_t)(m0 + row1) * 512 + k0 + c1);
            if (TERMS == 3) {
                rAl0 = *(const short8*)(Al + (size_t)(m0 + row0) * 512 + k0 + c0);
                rAl1 = *(const short8*)(Al + (size_t)(m0 + row1) * 512 + k0 + c1);
            }
        }
        rBh0 = *(const short8*)(Bh + (size_t)(n0 + row0) * 512 + k0 + c0);
        rBh1 = *(const short8*)(Bh + (size_t)(n0 + row1) * 512 + k0 + c1);
        if (TERMS >= 2) {
            rBl0 = *(const short8*)(Bl + (size_t)(n0 + row0) * 512 + k0 + c0);
            rBl1 = *(const short8*)(Bl + (size_t)(n0 + row1) * 512 + k0 + c1);
        }
    };
    auto STORE = [&]() {
        if (ACVT) {
            cvt8<TERMS == 3>(fA00, fA01, rAh0, rAl0);
            cvt8<TERMS == 3>(fA10, fA11, rAh1, rAl1);
        }
        *(short8*)&sAh[sa0] = rAh0;
        *(short8*)&sAh[sa1] = rAh1;
        if (TERMS == 3) {
            *(short8*)&sAl[sa0] = rAl0;
            *(short8*)&sAl[sa1] = rAl1;
        }
        *(short8*)&sBh[sa0] = rBh0;
        *(short8*)&sBh[sa1] = rBh1;
        if (TERMS >= 2) {
            *(short8*)&sBl[sa0] = rBl0;
            *(short8*)&sBl[sa1] = rBl1;
        }
    };

    int ra = wr * 64 + lrow;
    int rb = wc * 64 + lrow;
    int abase = ra * 32 + ((g ^ ((ra >> 1) & 3)) << 3);
    int bbase = rb * 32 + ((g ^ ((rb >> 1) & 3)) << 3);

    LOAD(0);
    for (int kt = 0; kt < 16; kt++) {
        STORE();
        __syncthreads();
        if (kt < 15) LOAD(kt + 1);
        short8 ah[4], al[4], bh[4], bl[4];
#pragma unroll
        for (int mf = 0; mf < 4; mf++) {
            ah[mf] = *(const short8*)&sAh[abase + mf * 512];
            if (TERMS == 3) al[mf] = *(const short8*)&sAl[abase + mf * 512];
        }
#pragma unroll
        for (int nf = 0; nf < 4; nf++) {
            bh[nf] = *(const short8*)&sBh[bbase + nf * 512];
            if (TERMS >= 2) bl[nf] = *(const short8*)&sBl[bbase + nf * 512];
        }
#pragma unroll
        for (int mf = 0; mf < 4; mf++)
#pragma unroll
            for (int nf = 0; nf < 4; nf++) {
                acc[mf][nf] = MFMA_BF16(ah[mf], bh[nf], acc[mf][nf]);
                if (TERMS >= 2) acc[mf][nf] = MFMA_BF16(ah[mf], bl[nf], acc[mf][nf]);
                if (TERMS == 3) acc[mf][nf] = MFMA_BF16(al[mf], bh[nf], acc[mf][nf]);
            }
        __syncthreads();
    }

    int crow0 = m0 + wr * 64 + (lane >> 4) * 4;
    int ccol0 = n0 + wc * 64 + lrow;
    float bb[4];
#pragma unroll
    for (int nf = 0; nf < 4; nf++) bb[nf] = bias[ccol0 + nf * 16];
#pragma unroll
    for (int mf = 0; mf < 4; mf++)
#pragma unroll
        for (int nf = 0; nf < 4; nf++)
#pragma unroll
            for (int r = 0; r < 4; r++) {
                float val = acc[mf][nf][r] + bb[nf];
                size_t idx = (size_t)(crow0 + mf * 16 + r) * 512 + ccol0 + nf * 16;
                if (OMODE != 2) C[idx] = val;
                if (OMODE != 0) Ch[idx] = f2bf(val);
            }
}

// ---------------- all-gload GEMM body (Q branch / F-GEMM; all operands bf16) ----
template<int TERMS, int OMODE>
__device__ __forceinline__
void gemm_body_gload(unsigned short* smem,
                     const unsigned short* __restrict__ Ah, const unsigned short* __restrict__ Al,
                     const unsigned short* __restrict__ Bh, const unsigned short* __restrict__ Bl,
                     const float* __restrict__ bias, float* __restrict__ C,
                     unsigned short* __restrict__ Ch, int orig) {
    unsigned short* sAh = smem;
    unsigned short* sAl = smem + ABUF;                            // TERMS==3 only
    unsigned short* sBh = smem + (TERMS == 3 ? 2 : 1) * ABUF;
    unsigned short* sBl = sBh + ABUF;                             // TERMS>=2 only

    int j = (orig & 7) * 64 + (orig >> 3);
    int n0 = (j & 3) * 128, m0 = (j >> 2) * 128;

    int tid = threadIdx.x;
    int lane = tid & 63, wv = tid >> 6;
    int wr = wv >> 1, wc = wv & 1;
    int lrow = lane & 15, g = lane >> 4;

    int r0 = wv * 16 + (lane >> 2);
    int r1 = r0 + 64;
    int kpos = lane & 3;
    int s0col = (kpos ^ ((r0 >> 1) & 3)) * 8;
    int s1col = (kpos ^ ((r1 >> 1) & 3)) * 8;

    f32x4 acc[4][4];
#pragma unroll
    for (int mf = 0; mf < 4; mf++)
#pragma unroll
        for (int nf = 0; nf < 4; nf++) acc[mf][nf] = (f32x4){0.f, 0.f, 0.f, 0.f};

    auto GLOAD_ALL = [&](int kt) {
        int k0 = kt * 32;
        gload16(Ah + (size_t)(m0 + r0) * 512 + k0 + s0col, sAh + wv * 512);
        gload16(Ah + (size_t)(m0 + r1) * 512 + k0 + s1col, sAh + 2048 + wv * 512);
        if (TERMS == 3) {
            gload16(Al + (size_t)(m0 + r0) * 512 + k0 + s0col, sAl + wv * 512);
            gload16(Al + (size_t)(m0 + r1) * 512 + k0 + s1col, sAl + 2048 + wv * 512);
        }
        gload16(Bh + (size_t)(n0 + r0) * 512 + k0 + s0col, sBh + wv * 512);
        gload16(Bh + (size_t)(n0 + r1) * 512 + k0 + s1col, sBh + 2048 + wv * 512);
        if (TERMS >= 2) {
            gload16(Bl + (size_t)(n0 + r0) * 512 + k0 + s0col, sBl + wv * 512);
            gload16(Bl + (size_t)(n0 + r1) * 512 + k0 + s1col, sBl + 2048 + wv * 512);
        }
    };

    int ra = wr * 64 + lrow;
    int rb = wc * 64 + lrow;
    int abase = ra * 32 + ((g ^ ((ra >> 1) & 3)) << 3);
    int bbase = rb * 32 + ((g ^ ((rb >> 1) & 3)) << 3);

    for (int kt = 0; kt < 16; kt++) {
        GLOAD_ALL(kt);
        __syncthreads();
        short8 ah[4], al[4], bh[4], bl[4];
#pragma unroll
        for (int mf = 0; mf < 4; mf++) {
            ah[mf] = *(const short8*)&sAh[abase + mf * 512];
            if (TERMS == 3) al[mf] = *(const short8*)&sAl[abase + mf * 512];
        }
#pragma unroll
        for (int nf = 0; nf < 4; nf++) {
            bh[nf] = *(const short8*)&sBh[bbase + nf * 512];
            if (TERMS >= 2) bl[nf] = *(const short8*)&sBl[bbase + nf * 512];
        }
#pragma unroll
        for (int mf = 0; mf < 4; mf++)
#pragma unroll
            for (int nf = 0; nf < 4; nf++) {
                acc[mf][nf] = MFMA_BF16(ah[mf], bh[nf], acc[mf][nf]);
                if (TERMS >= 2) acc[mf][nf] = MFMA_BF16(ah[mf], bl[nf], acc[mf][nf]);
                if (TERMS == 3) acc[mf][nf] = MFMA_BF16(al[mf], bh[nf], acc[mf][nf]);
            }
        __syncthreads();
    }

    int crow0 = m0 + wr * 64 + (lane >> 4) * 4;
    int ccol0 = n0 + wc * 64 + lrow;
    float bb[4];
#pragma unroll
    for (int nf = 0; nf < 4; nf++) bb[nf] = bias[ccol0 + nf * 16];
#pragma unroll
    for (int mf = 0; mf < 4; mf++)
#pragma unroll
        for (int nf = 0; nf < 4; nf++)
#pragma unroll
            for (int r = 0; r < 4; r++) {
                float val = acc[mf][nf][r] + bb[nf];
                size_t idx = (size_t)(crow0 + mf * 16 + r) * 512 + ccol0 + nf * 16;
                if (OMODE != 2) C[idx] = val;
                if (OMODE != 0) Ch[idx] = f2bf(val);
            }
}

// fused Q/K/V GEMM (blockIdx.z selects sub-GEMM); 32KB LDS
__global__ __launch_bounds__(256, 2)
void qkv_gemm(const unsigned short* __restrict__ lnq_h, const unsigned short* __restrict__ lnq_l,
              const float* __restrict__ keys, const float* __restrict__ values,
              const unsigned short* __restrict__ wq_h, const unsigned short* __restrict__ wq_l,
              const unsigned short* __restrict__ wk_h, const unsigned short* __restrict__ wk_l,
              const unsigned short* __restrict__ wv_h, const unsigned short* __restrict__ wv_l,
              const float* __restrict__ bq, const float* __restrict__ bk, const float* __restrict__ bv,
              float* __restrict__ qb, float* __restrict__ kb,
              unsigned short* __restrict__ kb_h, unsigned short* __restrict__ vb_h) {
    __shared__ __align__(16) unsigned short smem[4 * ABUF];  // 32KB
    int orig = blockIdx.x + 4 * blockIdx.y;
    if (blockIdx.z == 0)
        gemm_body_gload<3, 0>(smem, lnq_h, lnq_l, wq_h, wq_l, bq, qb, nullptr, orig);
    else if (blockIdx.z == 1)
        gemm_body<3, 1, 1>(smem, nullptr, nullptr, keys, wk_h, wk_l, bk, kb, kb_h, orig);
    else
        gemm_body<1, 2, 1>(smem, nullptr, nullptr, values, wv_h, wv_l, bv, nullptr, vb_h, orig);
}

// standalone F-GEMM: all-gload, 1-term -> 16KB LDS
__global__ __launch_bounds__(256, 2)
void fgemm_kernel(const unsigned short* __restrict__ Ah,
                  const unsigned short* __restrict__ Bh,
                  const float* __restrict__ bias, float* __restrict__ C) {
    __shared__ __align__(16) unsigned short smem[2 * ABUF];
    int orig = blockIdx.x + 4 * blockIdx.y;
    gemm_body_gload<1, 0>(smem, Ah, nullptr, Bh, nullptr, bias, C, nullptr, orig);
}

// ---------------- fused: sample_m | vsum ----------------
__global__ __launch_bounds__(256)
void sm_vsum_kernel(const float* __restrict__ q, const float* __restrict__ k,
                    const int* __restrict__ idx, float* __restrict__ M,
                    const unsigned short* __restrict__ vh, float* __restrict__ csum) {
    int bid = blockIdx.x;
    if (bid < 4096) {
        int b = bid & 7;
        int ig = bid >> 3;
        int wv = threadIdx.x >> 6, lane = threadIdx.x & 63;
        int i = ig * 4 + wv;
        const float* qrow = q + ((size_t)b * L + i) * DM + lane * 8;
        float4 q0 = *(const float4*)qrow;
        float4 q1 = *(const float4*)(qrow + 4);
        int myidx = 0;
        if (lane < SK) myidx = idx[i * SK + lane];
        float sj[SK];
#pragma unroll
        for (int j = 0; j < SK; j++) {
            int row = __shfl(myidx, j, 64);
            const float* kp = k + ((size_t)b * L + row) * DM + lane * 8;
            float4 k0 = *(const float4*)kp;
            float4 k1 = *(const float4*)(kp + 4);
            sj[j] = q0.x * k0.x + q0.y * k0.y + q0.z * k0.z + q0.w * k0.w
                  + q1.x * k1.x + q1.y * k1.y + q1.z * k1.z + q1.w * k1.w;
        }
        float mx = -1e30f, sm = 0.f;
#pragma unroll
        for (int j = 0; j < SK; j++) {
            float s = sj[j];
            s += __shfl_xor(s, 1, 64);
            s += __shfl_xor(s, 2, 64);
            s += __shfl_xor(s, 4, 64);
            mx = fmaxf(mx, s);
            sm += s;
        }
        if ((lane & 7) == 0) {
            int h = lane >> 3;
            M[((size_t)b * H_ + h) * L + i] = mx - sm * (1.0f / L);
        }
    } else {
        int t = bid - 4096;
        int c = t & (VC - 1), b = t >> 5;
        int d2 = threadIdx.x;
        size_t base = ((size_t)b * L + c * VR) * DM + d2 * 2;
        float a0 = 0.f, a1 = 0.f;
        for (int tt = 0; tt < VR; tt++) {
            unsigned v = *(const unsigned*)(vh + base + (size_t)tt * DM);
            a0 += bf2f((unsigned short)(v & 0xffff));
            a1 += bf2f((unsigned short)(v >> 16));
        }
        float2 st = {a0, a1};
        *(float2*)(csum + ((size_t)b * VC + c) * DM + d2 * 2) = st;
    }
}

// ---------------- fused: topk+qprep | vavg ----------------
// blocks 0..63: wave 0 does register top-k, then ALL 4 waves gather/scale the
// selected Q rows (8 rows per wave, 64 lanes each) -> removes qprep launch.
__global__ __launch_bounds__(256)
void topk_vavg_kernel(const float* __restrict__ M, int* __restrict__ mtop,
                      const float* __restrict__ qb, const float* __restrict__ pad,
                      unsigned short* __restrict__ qsel, int* __restrict__ lim_arr,
                      const unsigned short* __restrict__ vh, const float* __restrict__ csum,
                      const float* __restrict__ denom, unsigned short* __restrict__ out_h) {
    int bid = blockIdx.x;
    if (bid < 64) {
        int bh = bid;
        int b = bh >> 3, h = bh & 7;
        int wv = threadIdx.x >> 6, lane = threadIdx.x & 63;
        __shared__ int sel_s[NTOP];
        if (wv == 0) {
            const float* Mr = M + (size_t)bh * L;
            float m[32];
#pragma unroll
            for (int r = 0; r < 32; r++) m[r] = Mr[r * 64 + lane];
            for (int it = 0; it < NTOP; it++) {
                float bv = -1e30f; int br = 0;
#pragma unroll
                for (int r = 0; r < 32; r++) {
                    bool better = m[r] > bv;   // strict > keeps lowest r on ties
                    br = better ? r : br;
                    bv = better ? m[r] : bv;
                }
                int bt = (br << 6) | lane;
#pragma unroll
                for (int o = 1; o < 64; o <<= 1) {
                    float ov = __shfl_xor(bv, o, 64);
                    int ot = __shfl_xor(bt, o, 64);
                    bool take = (ov > bv) || (ov == bv && ot < bt);
                    bv = take ? ov : bv;
                    bt = take ? ot : bt;
                }
                if (lane == 0) { mtop[bh * NTOP + it] = bt; sel_s[it] = bt; }
                int rwin = bt >> 6;
                bool mine = (bt & 63) == lane;
#pragma unroll
                for (int r = 0; r < 32; r++)
                    if (mine && (r == rwin)) m[r] = -1e30f;
            }
        }
        __syncthreads();
        // phase 2: all 4 waves gather selected Q rows (u = wv, wv+4, ...)
        for (int u = wv; u < 32; u += 4) {
            if (u < NTOP) {
                int iq = sel_s[u];
                bool ok = pad[(size_t)b * L + iq] != 0.f;
                float sc = ok ? 0.044194173824159216f : 0.f;
                float qv = qb[((size_t)b * L + iq) * DM + h * DH + lane];
                qsel[((size_t)bh * 32 + u) * 64 + lane] = f2bf(qv * sc);
                if (lane == 0) lim_arr[bh * 32 + u] = ok ? iq : (L - 1);
            } else {
                qsel[((size_t)bh * 32 + u) * 64 + lane] = 0;
                if (lane == 0) lim_arr[bh * 32 + u] = -1;
            }
        }
    } else {
        int t = bid - 64;
        int c = t & (VC - 1), b = t >> 5;
        int d2 = threadIdx.x;
        float a0 = 0.f, a1 = 0.f;
        for (int cc = 0; cc < c; cc++) {
            float2 tt = *(const float2*)(csum + ((size_t)b * VC + cc) * DM + d2 * 2);
            a0 += tt.x; a1 += tt.y;
        }
        size_t base = ((size_t)b * L + c * VR) * DM + d2 * 2;
        for (int tt = 0; tt < VR; tt++) {
            unsigned v = *(const unsigned*)(vh + base + (size_t)tt * DM);
            a0 += bf2f((unsigned short)(v & 0xffff));
            a1 += bf2f((unsigned short)(v >> 16));
            float dn = denom[(size_t)b * L + c * VR + tt] + 1e-12f;
            unsigned o = (unsigned)f2bf(a0 / dn) | ((unsigned)f2bf(a1 / dn) << 16);
            *(unsigned*)(out_h + base + (size_t)tt * DM) = o;
        }
    }
}

// ---------------- MFMA split-chunk sparse attention ----------------
__global__ __launch_bounds__(256)
void attn_chunk_mfma(const unsigned short* __restrict__ kbh,
                     const unsigned short* __restrict__ vbh,
                     const unsigned short* __restrict__ qsel,
                     const int* __restrict__ lim_arr,
                     float* __restrict__ part_m, float* __restrict__ part_s,
                     float* __restrict__ part_acc) {
    int c = blockIdx.x, bh = blockIdx.y;
    int b = bh >> 3, h = bh & 7;
    int j0 = c * CHUNK;
    __shared__ __align__(16) unsigned short KV[128 * 64];
    __shared__ __align__(16) unsigned short Ps[32 * 128];
    __shared__ __align__(16) unsigned short Qs[32 * 64];
    __shared__ float redm[4][32];
    __shared__ float reds[4][32];
    __shared__ int lims[32];

    int tid = threadIdx.x;
    int wv = tid >> 6, lane = tid & 63;
    int l15 = lane & 15, g = lane >> 4;

    const unsigned short* kpanel = kbh + ((size_t)b * L + j0) * DM + h * DH;
    short8 kreg[4];
#pragma unroll
    for (int l = 0; l < 4; l++) {
        int f = tid + l * 256;
        int jr = f >> 3, blk = f & 7;
        kreg[l] = *(const short8*)(kpanel + (size_t)jr * DM + blk * 8);
    }
    {
        int u = tid >> 3, blk = tid & 7;
        short8 qreg = *(const short8*)(qsel + ((size_t)bh * 32 + u) * 64 + blk * 8);
        *(short8*)&Qs[u * 64 + (((blk ^ (u & 7))) << 3)] = qreg;
    }
#pragma unroll
    for (int l = 0; l < 4; l++) {
        int f = tid + l * 256;
        int jr = f >> 3, blk = f & 7;
        *(short8*)&KV[jr * 64 + ((blk ^ (jr & 7)) << 3)] = kreg[l];
    }
    if (tid < 32) lims[tid] = lim_arr[bh * 32 + tid];
    __syncthreads();

    f32x4 sf[2][2];
#pragma unroll
    for (int mf = 0; mf < 2; mf++)
#pragma unroll
        for (int nf = 0; nf < 2; nf++) sf[mf][nf] = (f32x4){0.f, 0.f, 0.f, 0.f};
#pragma unroll
    for (int ks = 0; ks < 2; ks++) {
        short8 aq[2], bk[2];
#pragma unroll
        for (int mf = 0; mf < 2; mf++) {
            int u = mf * 16 + l15;
            int blk = (ks * 4 + g) ^ (u & 7);
            aq[mf] = *(const short8*)&Qs[u * 64 + (blk << 3)];
        }
#pragma unroll
        for (int nf = 0; nf < 2; nf++) {
            int jr = wv * 32 + nf * 16 + l15;
            int blk = (ks * 4 + g) ^ (jr & 7);
            bk[nf] = *(const short8*)&KV[jr * 64 + (blk << 3)];
        }
#pragma unroll
        for (int mf = 0; mf < 2; mf++)
#pragma unroll
            for (int nf = 0; nf < 2; nf++)
                sf[mf][nf] = MFMA_BF16(aq[mf], bk[nf], sf[mf][nf]);
    }

    const unsigned short* vpanel = vbh + ((size_t)b * L + j0) * DM + h * DH;
    short8 vreg[4];
#pragma unroll
    for (int l = 0; l < 4; l++) {
        int f = tid + l * 256;
        int jr = f >> 3, blk = f & 7;
        vreg[l] = *(const short8*)(vpanel + (size_t)jr * DM + blk * 8);
    }

    float sv[2][2][4];
    float mx[2][4];
#pragma unroll
    for (int mf = 0; mf < 2; mf++)
#pragma unroll
        for (int r = 0; r < 4; r++) {
            int u = mf * 16 + g * 4 + r;
            int limv = lims[u];
            float m = -1e30f;
#pragma unroll
            for (int nf = 0; nf < 2; nf++) {
                int jg = j0 + wv * 32 + nf * 16 + l15;
                float s = (jg <= limv) ? sf[mf][nf][r] : -1e30f;
                sv[mf][nf][r] = s;
                m = fmaxf(m, s);
            }
            m = fmaxf(m, __shfl_xor(m, 1, 64));
            m = fmaxf(m, __shfl_xor(m, 2, 64));
            m = fmaxf(m, __shfl_xor(m, 4, 64));
            m = fmaxf(m, __shfl_xor(m, 8, 64));
            mx[mf][r] = m;
        }
    if (l15 == 0) {
#pragma unroll
        for (int mf = 0; mf < 2; mf++)
#pragma unroll
            for (int r = 0; r < 4; r++)
                redm[wv][mf * 16 + g * 4 + r] = mx[mf][r];
    }
    __syncthreads();

    float lmax[2][4], smv[2][4];
#pragma unroll
    for (int mf = 0; mf < 2; mf++)
#pragma unroll
        for (int r = 0; r < 4; r++) {
            int u = mf * 16 + g * 4 + r;
            float m = fmaxf(fmaxf(redm[0][u], redm[1][u]),
                            fmaxf(redm[2][u], redm[3][u]));
            lmax[mf][r] = m;
            bool any = m > -1e29f;
            float sm = 0.f;
#pragma unroll
            for (int nf = 0; nf < 2; nf++) {
                float e = any ? __expf(sv[mf][nf][r] - m) : 0.f;
                sm += e;
                int jr = wv * 32 + nf * 16 + l15;
                Ps[u * 128 + (((jr >> 3) ^ (u & 7)) << 3) + (jr & 7)] = f2bf(e);
            }
            sm += __shfl_xor(sm, 1, 64);
            sm += __shfl_xor(sm, 2, 64);
            sm += __shfl_xor(sm, 4, 64);
            sm += __shfl_xor(sm, 8, 64);
            smv[mf][r] = sm;
        }
    if (l15 == 0) {
#pragma unroll
        for (int mf = 0; mf < 2; mf++)
#pragma unroll
            for (int r = 0; r < 4; r++)
                reds[wv][mf * 16 + g * 4 + r] = smv[mf][r];
    }
#pragma unroll
    for (int l = 0; l < 4; l++) {
        int f = tid + l * 256;
        int jr = f >> 3, blk = f & 7;
        short8 w = vreg[l];
        if ((jr >> 3) & 1) w = __builtin_shufflevector(w, w, 4, 5, 6, 7, 0, 1, 2, 3);
        *(short8*)&KV[jr * 64 + ((blk ^ (jr & 7)) << 3)] = w;
    }
    __syncthreads();

    if (wv == 0 && l15 == 0) {
#pragma unroll
        for (int mf = 0; mf < 2; mf++)
#pragma unroll
            for (int r = 0; r < 4; r++) {
                int u = mf * 16 + g * 4 + r;
                if (u < NTOP) {
                    float ss = reds[0][u] + reds[1][u] + reds[2][u] + reds[3][u];
                    part_m[(bh * NTOP + u) * NCH + c] = lmax[mf][r];
                    part_s[(bh * NTOP + u) * NCH + c] = ss;
                }
            }
    }

    f32x4 of[2];
    of[0] = (f32x4){0.f, 0.f, 0.f, 0.f};
    of[1] = (f32x4){0.f, 0.f, 0.f, 0.f};
    int d = wv * 16 + l15;
#pragma unroll
    for (int ks = 0; ks < 4; ks++) {
        unsigned short va[8];
#pragma unroll
        for (int i = 0; i < 8; i++) {
            int jr = ks * 32 + g * 8 + i;
            int addr = jr * 64 + (((d >> 3) ^ (jr & 7)) << 3)
                     + ((d & 7) ^ (((jr >> 3) & 1) << 2));
            va[i] = KV[addr];
        }
        short8 av;
#pragma unroll
        for (int i = 0; i < 8; i++) av[i] = (short)va[i];
        short8 bp[2];
#pragma unroll
        for (int nf = 0; nf < 2; nf++) {
            int u = nf * 16 + l15;
            int blk = (ks * 4 + g) ^ (u & 7);
            bp[nf] = *(const short8*)&Ps[u * 128 + (blk << 3)];
        }
#pragma unroll
        for (int nf = 0; nf < 2; nf++)
            of[nf] = MFMA_BF16(av, bp[nf], of[nf]);
    }
#pragma unroll
    for (int nf = 0; nf < 2; nf++) {
        int u = nf * 16 + l15;
        if (u < NTOP) {
#pragma unroll
            for (int r = 0; r < 4; r++)
                part_acc[((size_t)(bh * NTOP + u) * NCH + c) * 64 + wv * 16 + g * 4 + r] =
                    of[nf][r];
        }
    }
}

// merge 16 chunk partials per (bh,u); scatter bf16 into pre_h
__global__ __launch_bounds__(256)
void attn_merge_kernel(const float* __restrict__ part_m, const float* __restrict__ part_s,
                       const float* __restrict__ part_acc, const int* __restrict__ mtop,
                       unsigned short* __restrict__ pre_h) {
    int ug = blockIdx.x;
    int bh = blockIdx.y;
    int b = bh >> 3, h = bh & 7;
    int tid = threadIdx.x;
    int u = ug * 4 + (tid >> 6);
    int d = tid & 63;
    int base = (bh * NTOP + u) * NCH;
    float m = -1e30f;
#pragma unroll
    for (int c = 0; c < NCH; c++) m = fmaxf(m, part_m[base + c]);
    float s = 0.f, o = 0.f;
#pragma unroll
    for (int c = 0; c < NCH; c++) {
        float w = __expf(part_m[base + c] - m);
        s += part_s[base + c] * w;
        o = fmaf(part_acc[(size_t)(base + c) * 64 + d], w, o);
    }
    o /= s;
    int iq = mtop[bh * NTOP + u];
    pre_h[((size_t)b * L + iq) * DM + h * DH + d] = f2bf(o);
}

// ---------------- final LayerNorm (row-wise, 512 cols) ----------------
__global__ __launch_bounds__(256)
void ln_kernel(const float* __restrict__ x, const float* __restrict__ w,
               const float* __restrict__ bvec, float* __restrict__ out) {
    int row = blockIdx.x;
    const float* xr = x + (size_t)row * DM;
    float* orow = out + (size_t)row * DM;
    int tid = threadIdx.x;
    float2 v = *(const float2*)(xr + tid * 2);
    float s = v.x + v.y;
    float sq = v.x * v.x + v.y * v.y;
    __shared__ float red[8];
    float ws = waveReduceSum(s);
    float wq = waveReduceSum(sq);
    int wid = tid >> 6, lane = tid & 63;
    if (lane == 0) { red[wid] = ws; red[4 + wid] = wq; }
    __syncthreads();
    float tot = red[0] + red[1] + red[2] + red[3];
    float totq = red[4] + red[5] + red[6] + red[7];
    float mean = tot * (1.0f / DM);
    float var = totq * (1.0f / DM) - mean * mean;
    float inv = rsqrtf(var + 1e-8f);
    float w0 = w[tid * 2], w1 = w[tid * 2 + 1];
    float b0 = bvec[tid * 2], b1 = bvec[tid * 2 + 1];
    float2 o;
    o.x = w0 * (v.x - mean) * inv + b0;
    o.y = w1 * (v.y - mean) * inv + b1;
    *(float2*)(orow + tid * 2) = o;
}

extern "C" void kernel_launch(void* const* d_in, const int* in_sizes, int n_in,
                              void* d_out, int out_size, void* d_ws, size_t ws_size,
                              hipStream_t stream) {
    const float* queries = (const float*)d_in[0];
    const float* keys    = (const float*)d_in[1];
    const float* values  = (const float*)d_in[2];
    const float* pad     = (const float*)d_in[3];
    const float* Wq = (const float*)d_in[4];  const float* bq = (const float*)d_in[5];
    const float* Wk = (const float*)d_in[6];  const float* bk = (const float*)d_in[7];
    const float* Wv = (const float*)d_in[8];  const float* bv = (const float*)d_in[9];
    const float* Wf = (const float*)d_in[10]; const float* bfv = (const float*)d_in[11];
    const float* qlnw = (const float*)d_in[12]; const float* qlnb = (const float*)d_in[13];
    const float* flnw = (const float*)d_in[14]; const float* flnb = (const float*)d_in[15];
    const int* idx = (const int*)d_in[16];

    float* ws = (float*)d_ws;
    const size_t NE = (size_t)B_ * L * DM;   // 8388608
    float* qb    = ws;
    float* kb    = ws + NE;
    unsigned short* vb_h = (unsigned short*)(ws + 2 * NE);   // NE u16
    unsigned short* kb_h = vb_h + NE;                        // NE u16
    unsigned short* qsel = (unsigned short*)(ws + 3 * NE);   // 64*32*64 u16
    int* lim_arr = (int*)(qsel + 64 * 32 * 64);              // 2048 ints
    float* Mbuf  = ws + 4 * NE;                      // 64*2048
    float* denom = Mbuf + (size_t)B_ * H_ * L;       // 8*2048
    float* csum  = denom + (size_t)B_ * L;           // 8*32*512
    int*   mtop  = (int*)(csum + (size_t)B_ * VC * DM);
    unsigned short* bfr = (unsigned short*)(mtop + 2048);
    unsigned short* pre_h = bfr;                     // NE u16
    unsigned short* wts   = bfr + NE;                // 8 x 262144 u16
    unsigned short* wq_h = wts;              unsigned short* wq_l = wts + 262144;
    unsigned short* wk_h = wts + 2 * 262144; unsigned short* wk_l = wts + 3 * 262144;
    unsigned short* wv_h = wts + 4 * 262144; unsigned short* wv_l = wts + 5 * 262144;
    unsigned short* wf_h = wts + 6 * 262144; unsigned short* wf_l = wts + 7 * 262144;

    float* tmp = (float*)d_out;
    unsigned short* lnq_h = (unsigned short*)d_out;   // d_out as bf16 scratch
    unsigned short* lnq_l = lnq_h + NE;
    float* part_m   = tmp;                            // later: attn partials
    float* part_s   = part_m + 64 * NTOP * NCH;
    float* part_acc = part_s + 64 * NTOP * NCH;

    // fused preprocessing: ln_split (16384) + wsplit x4 (1024) + padscan (8)
    prep_kernel<<<16384 + 1024 + 8, 256, 0, stream>>>(
        queries, qlnw, qlnb, lnq_h, lnq_l, Wq, Wk, Wv, Wf, wts, pad, denom);

    dim3 gq(4, 128, 3);
    qkv_gemm<<<gq, 256, 0, stream>>>(lnq_h, lnq_l, keys, values,
                                     wq_h, wq_l, wk_h, wk_l, wv_h, wv_l,
                                     bq, bk, bv, qb, kb, kb_h, vb_h);

    sm_vsum_kernel<<<4096 + 256, 256, 0, stream>>>(qb, kb, idx, Mbuf, vb_h, csum);
    // fused: topk+qprep (64) + vavg (256)
    topk_vavg_kernel<<<64 + 256, 256, 0, stream>>>(Mbuf, mtop, qb, pad, qsel, lim_arr,
                                                   vb_h, csum, denom, pre_h);
    dim3 gc(NCH, 64);
    attn_chunk_mfma<<<gc, 256, 0, stream>>>(kb_h, vb_h, qsel, lim_arr,
                                            part_m, part_s, part_acc);
    dim3 gmg(6, 64);
    attn_merge_kernel<<<gmg, 256, 0, stream>>>(part_m, part_s, part_acc, mtop, pre_h);
    dim3 gg(4, 128);
    fgemm_kernel<<<gg, 256, 0, stream>>>(pre_h, wf_h, bfv, (float*)d_out);
    ln_kernel<<<B_ * L, 256, 0, stream>>>((float*)d_out, flnw, flnb, (float*)d_out);
}